// Round 6
// baseline (2835.440 us; speedup 1.0000x reference)
//
#include <hip/hip_runtime.h>

typedef unsigned short u16;
typedef unsigned int u32;
using bf16x8 = __attribute__((ext_vector_type(8))) short;
using f32x4 = __attribute__((ext_vector_type(4))) float;

constexpr int kL = 8192;
constexpr int kDIM = 256;
constexpr int kDI = 512;
constexpr int kNB = 8;
constexpr float kEPS = 1e-3f;

__device__ __forceinline__ u16 f2b(float f) {
  u32 x = __builtin_bit_cast(u32, f);
  x += 0x7fffu + ((x >> 16) & 1u);
  return (u16)(x >> 16);
}
__device__ __forceinline__ float b2f(u16 u) {
  return __builtin_bit_cast(float, (u32)u << 16);
}
__device__ __forceinline__ float sigm(float x) { return 1.f / (1.f + __expf(-x)); }
__device__ __forceinline__ float softplus_fast(float x) {
  return fmaxf(x, 0.f) + __logf(1.f + __expf(-fabsf(x)));
}

__device__ __forceinline__ void async_cp16(const void* g, void* l) {
  __builtin_amdgcn_global_load_lds((const __attribute__((address_space(1))) u32*)g,
                                   (__attribute__((address_space(3))) u32*)l, 16, 0, 0);
}

// ---------------- balanced vectorized weight conversion ----------------
// mode 0: identity.
// mode 1: gu 16-wide interleave with expert grouping:
//   src row (e*512 + j) -> dst row e*1024 + (j>>4)*32 + (j&15)  (u: dst ptr pre-offset +16 rows)
// mode 2: dproj permute (NB,NE,DIM,INNER) -> (NB, DIM, NE*INNER).
struct Cvt2 {
  const float* s[23];
  u16* d[23];
  int n[23];
  int mode[23];
  int bstart[24];
  int nseg;
};
__global__ __launch_bounds__(256) void cvt2_k(Cvt2 dd) {
  const int b = blockIdx.x;
  int seg = 0;
  for (int i = 1; i < dd.nseg; ++i) seg += (b >= dd.bstart[i]) ? 1 : 0;
  const int lb = b - dd.bstart[seg];
  const float* s = dd.s[seg];
  u16* d = dd.d[seg];
  const int n = dd.n[seg];
  const int mode = dd.mode[seg];
  #pragma unroll
  for (int it = 0; it < 4; ++it) {
    const int e4 = lb * 1024 + it * 256 + threadIdx.x;
    const int i = e4 * 4;
    if (i >= n) break;
    const float4 v = ((const float4*)s)[e4];
    ushort4 o = make_ushort4(f2b(v.x), f2b(v.y), f2b(v.z), f2b(v.w));
    size_t dst;
    if (mode == 0) {
      dst = (size_t)i;
    } else if (mode == 1) {
      const int row = i >> 8, col = i & 255;
      const int drow = (row >> 9) * 1024 + ((row >> 4) & 31) * 32 + (row & 15);
      dst = (size_t)drow * 256 + col;
    } else {
      const int bb = i >> 19, e = (i >> 17) & 3, nr = (i >> 9) & 255, j = i & 511;
      dst = (size_t)bb * 524288 + (size_t)nr * 2048 + e * 512 + j;
    }
    *(ushort4*)&d[dst] = o;
  }
}

// x (DIM, L) f32 -> xT (L, DIM) bf16
__global__ __launch_bounds__(256) void transpose_x_k(const float* __restrict__ x, u16* __restrict__ xT) {
  __shared__ float tile[32][33];
  int l0 = blockIdx.x * 32, d0 = blockIdx.y * 32;
  int tx = threadIdx.x, ty = threadIdx.y;
  #pragma unroll
  for (int i = 0; i < 32; i += 8)
    tile[ty + i][tx] = x[(size_t)(d0 + ty + i) * kL + l0 + tx];
  __syncthreads();
  #pragma unroll
  for (int i = 0; i < 32; i += 8)
    xT[(size_t)(l0 + ty + i) * kDIM + d0 + tx] = f2b(tile[tx][ty + i]);
}

// ---------------- templated MFMA GEMM: C(MxN) = A(MxK) @ W(NxK)^T ----------------
// MODE 0: f32 store; 2: bf16 store; 3: silu->bf16; 4: f32 atomicAdd (split-K);
// MODE 5: f32 partial store at C + blockIdx.z*pstride; MODE 7: sigmoid + transposed store.
template <int BM, int BN, int TR, int TC, int WCN, int MODE>
__global__ __launch_bounds__(256) void gemm_t(
    const u16* __restrict__ A, int lda,
    const u16* __restrict__ W, int ldw,
    void* __restrict__ C, int ldc,
    int N, int K, int pstride)
{
  constexpr int BNR = (BN + 63) & ~63;
  __shared__ u16 As[BM * 64];
  __shared__ u16 Bs[BNR * 64];
  const int tid = threadIdx.x;
  const int lane = tid & 63;
  const int wave = tid >> 6;
  const int bm = blockIdx.x * BM;
  const int bn = blockIdx.y * BN;
  const int wrow = (wave / WCN) * (TR * 16);
  const int wcol = (wave % WCN) * (TC * 16);
  const int kchunk = K / (int)gridDim.z;
  const int kbeg = blockIdx.z * kchunk;
  const int kend = kbeg + kchunk;

  f32x4 acc[TR][TC];
  #pragma unroll
  for (int r = 0; r < TR; ++r)
    #pragma unroll
    for (int c = 0; c < TC; ++c)
      acc[r][c] = f32x4{0.f, 0.f, 0.f, 0.f};

  for (int k0 = kbeg; k0 < kend; k0 += 64) {
    #pragma unroll
    for (int it = 0; it < BM * 64 / 2048; ++it) {
      int flat = (it * 256 + tid) * 8;
      int r = flat >> 6;
      int gc = ((((flat >> 3) & 7) ^ (r & 7)) << 3);
      async_cp16(A + (size_t)(bm + r) * lda + k0 + gc, &As[flat]);
    }
    #pragma unroll
    for (int it = 0; it < BNR * 64 / 2048; ++it) {
      int flat = (it * 256 + tid) * 8;
      int r = flat >> 6;
      int gc = ((((flat >> 3) & 7) ^ (r & 7)) << 3);
      int n = bn + r;
      if (n > N - 1) n = N - 1;
      async_cp16(W + (size_t)n * ldw + k0 + gc, &Bs[flat]);
    }
    __syncthreads();
    #pragma unroll
    for (int kk = 0; kk < 64; kk += 32) {
      const int kc = (kk >> 3) + (lane >> 4);
      const int mrow = lane & 15;
      bf16x8 a[TR], b[TC];
      #pragma unroll
      for (int rr = 0; rr < TR; ++rr) {
        int row = wrow + rr * 16 + mrow;
        a[rr] = *(const bf16x8*)&As[row * 64 + ((kc ^ (row & 7)) << 3)];
      }
      #pragma unroll
      for (int cc = 0; cc < TC; ++cc) {
        int row = wcol + cc * 16 + mrow;
        b[cc] = *(const bf16x8*)&Bs[row * 64 + ((kc ^ (row & 7)) << 3)];
      }
      #pragma unroll
      for (int rr = 0; rr < TR; ++rr)
        #pragma unroll
        for (int cc = 0; cc < TC; ++cc)
          acc[rr][cc] = __builtin_amdgcn_mfma_f32_16x16x32_bf16(a[rr], b[cc], acc[rr][cc], 0, 0, 0);
    }
    __syncthreads();
  }

  const int colb = bn + wcol + (lane & 15);
  const int rowb = bm + wrow + ((lane >> 4) << 2);
  #pragma unroll
  for (int rr = 0; rr < TR; ++rr)
    #pragma unroll
    for (int cc = 0; cc < TC; ++cc) {
      int col = colb + cc * 16;
      if (col >= N) continue;
      #pragma unroll
      for (int i = 0; i < 4; ++i) {
        const int row = rowb + rr * 16 + i;
        size_t off = (size_t)row * ldc + col;
        float v = acc[rr][cc][i];
        if constexpr (MODE == 0) ((float*)C)[off] = v;
        else if constexpr (MODE == 2) ((u16*)C)[off] = f2b(v);
        else if constexpr (MODE == 3) ((u16*)C)[off] = f2b(v * sigm(v));
        else if constexpr (MODE == 4) atomicAdd(&((float*)C)[off], v);
        else if constexpr (MODE == 5) ((float*)C)[off + (size_t)blockIdx.z * pstride] = v;
        else if constexpr (MODE == 7) ((float*)C)[(size_t)col * kL + row] = sigm(v);
      }
    }
}

// ---------------- fused MoE mega-kernel, barrier-light ----------------
// 256 blocks x 512 threads (8 waves), 32 rows of h per block.
// B operands are read DIRECTLY from global (L2-resident weights) — no LDS staging,
// so phases have no internal barriers; only 2 __syncthreads per expert.
// phase -1: hv = h + sum(hpart); router top2 -> WeS; Ah = bf16(hv) in LDS.
// phase 1 (per expert): wave w computes 32 gu-cols per nc chunk from Ah(LDS) x Wgu(global);
//                       GLU mix -> Ts (LDS).
// phase 2 (per expert): macc += Ts(LDS) @ Wd_e(global)^T, K=512.
// epilogue: rms_f + residual + rms_a, write h, hb2, hn.
__global__ __launch_bounds__(512, 4) void moe_mega_k(
    float* __restrict__ h, const float* __restrict__ hpart,
    const float* __restrict__ gw,
    const u16* __restrict__ Wgu, const u16* __restrict__ Wd,
    const float* __restrict__ wf, const float* __restrict__ wa,
    u16* __restrict__ hb2, u16* __restrict__ hn)
{
  __shared__ u16 Ah[32 * 256];       // 16 KB, swizzled 16B chunks: chunk ^ (row&7)
  __shared__ u16 Ts[32 * 512];       // 32 KB, swizzled (epilogue overlays f32 MoeS)
  __shared__ float WeS[32][4];
  const int tid = threadIdx.x;
  const int lane = tid & 63;
  const int quad = lane >> 4;
  const int m16 = lane & 15;
  const int wave = tid >> 6;         // 0..7
  const int r0 = blockIdx.x * 32;
  const int prow = tid >> 4;         // 0..31
  const int pcol = (tid & 15) * 16;

  // ---- phase -1 ----
  float hv[16];
  {
    const size_t base = (size_t)(r0 + prow) * 256 + pcol;
    #pragma unroll
    for (int j = 0; j < 16; j += 4) {
      float4 v = *(const float4*)(h + base + j);
      #pragma unroll
      for (int z = 0; z < 4; ++z) {
        const float4 pv = *(const float4*)(hpart + (size_t)z * 2097152 + base + j);
        v.x += pv.x; v.y += pv.y; v.z += pv.z; v.w += pv.w;
      }
      hv[j] = v.x; hv[j + 1] = v.y; hv[j + 2] = v.z; hv[j + 3] = v.w;
    }
  }
  {
    float p[4];
    #pragma unroll
    for (int e = 0; e < 4; ++e) {
      float s = 0.f;
      #pragma unroll
      for (int j = 0; j < 16; ++j) s += hv[j] * gw[e * 256 + pcol + j];
      p[e] = s;
    }
    #pragma unroll
    for (int o = 8; o > 0; o >>= 1) {
      p[0] += __shfl_xor(p[0], o); p[1] += __shfl_xor(p[1], o);
      p[2] += __shfl_xor(p[2], o); p[3] += __shfl_xor(p[3], o);
    }
    if ((tid & 15) == 0) {
      int i0 = 0;
      #pragma unroll
      for (int e = 1; e < 4; ++e) if (p[e] > p[i0]) i0 = e;
      int i1 = -1;
      #pragma unroll
      for (int e = 0; e < 4; ++e) {
        if (e == i0) continue;
        if (i1 < 0 || p[e] > p[i1]) i1 = e;
      }
      const float tt = __expf(p[i1] - p[i0]);
      float o0 = 1.f / (1.f + tt), o1 = tt / (1.f + tt);
      WeS[prow][0] = 0.f; WeS[prow][1] = 0.f; WeS[prow][2] = 0.f; WeS[prow][3] = 0.f;
      WeS[prow][i0] = o0; WeS[prow][i1] = o1;
    }
    // Ah store (swizzled)
    #pragma unroll
    for (int cc = 0; cc < 2; ++cc) {
      const int chunk = (pcol >> 3) + cc;
      const int sw = ((chunk ^ (prow & 7)) << 3);
      u16 tmp[8];
      #pragma unroll
      for (int j = 0; j < 8; ++j) tmp[j] = f2b(hv[cc * 8 + j]);
      *(bf16x8*)&Ah[prow * 256 + sw] = *(bf16x8*)tmp;
    }
  }
  __syncthreads();

  f32x4 macc[2][2];
  #pragma unroll
  for (int rt = 0; rt < 2; ++rt)
    #pragma unroll
    for (int ct = 0; ct < 2; ++ct) macc[rt][ct] = f32x4{0.f, 0.f, 0.f, 0.f};

  for (int e = 0; e < 4; ++e) {
    // ---- phase 1: no internal barriers ----
    #pragma unroll
    for (int nc = 0; nc < 4; ++nc) {
      f32x4 acc[2][2];
      #pragma unroll
      for (int rt = 0; rt < 2; ++rt)
        #pragma unroll
        for (int ct = 0; ct < 2; ++ct) acc[rt][ct] = f32x4{0.f, 0.f, 0.f, 0.f};
      const u16* wbase = Wgu + (size_t)(e * 1024 + nc * 256 + wave * 32) * 256;
      #pragma unroll
      for (int k0 = 0; k0 < 256; k0 += 32) {
        const int ch = (k0 >> 3) + quad;
        bf16x8 a[2], b[2];
        #pragma unroll
        for (int rt = 0; rt < 2; ++rt) {
          const int row = rt * 16 + m16;
          a[rt] = *(const bf16x8*)&Ah[row * 256 + ((ch ^ (row & 7)) << 3)];
        }
        #pragma unroll
        for (int ct = 0; ct < 2; ++ct)
          b[ct] = *(const bf16x8*)&wbase[(ct * 16 + m16) * 256 + k0 + quad * 8];
        #pragma unroll
        for (int rt = 0; rt < 2; ++rt)
          #pragma unroll
          for (int ct = 0; ct < 2; ++ct)
            acc[rt][ct] = __builtin_amdgcn_mfma_f32_16x16x32_bf16(a[rt], b[ct], acc[rt][ct], 0, 0, 0);
      }
      // GLU mix -> Ts (g = acc[rt][0], u = acc[rt][1]; same lane holds the pair)
      const int group = nc * 8 + wave;
      const int j = group * 16 + m16;
      #pragma unroll
      for (int rt = 0; rt < 2; ++rt)
        #pragma unroll
        for (int i = 0; i < 4; ++i) {
          const int row = rt * 16 + quad * 4 + i;
          const float g = acc[rt][0][i];
          const float u = acc[rt][1][i];
          const float val = g * sigm(g) * u * WeS[row][e];
          Ts[row * 512 + (((j >> 3) ^ (row & 7)) << 3) + (j & 7)] = f2b(val);
        }
    }
    __syncthreads();  // Ts complete
    // ---- phase 2: no internal barriers ----
    const u16* dbase = Wd + (size_t)(wave * 32) * 2048 + e * 512;
    #pragma unroll
    for (int k0 = 0; k0 < 512; k0 += 32) {
      const int ch = (k0 >> 3) + quad;
      bf16x8 a[2], b[2];
      #pragma unroll
      for (int rt = 0; rt < 2; ++rt) {
        const int row = rt * 16 + m16;
        a[rt] = *(const bf16x8*)&Ts[row * 512 + ((ch ^ (row & 7)) << 3)];
      }
      #pragma unroll
      for (int ct = 0; ct < 2; ++ct)
        b[ct] = *(const bf16x8*)&dbase[(ct * 16 + m16) * 2048 + k0 + quad * 8];
      #pragma unroll
      for (int rt = 0; rt < 2; ++rt)
        #pragma unroll
        for (int ct = 0; ct < 2; ++ct)
          macc[rt][ct] = __builtin_amdgcn_mfma_f32_16x16x32_bf16(a[rt], b[ct], macc[rt][ct], 0, 0, 0);
    }
    __syncthreads();  // Ts consumed; next expert may overwrite
  }

  // ---- epilogue: macc -> LDS (row-major f32 overlay on Ts), dual rmsnorm, stores ----
  float* MoeS = (float*)Ts;  // 32x256 f32 = 32 KB
  #pragma unroll
  for (int rt = 0; rt < 2; ++rt)
    #pragma unroll
    for (int ct = 0; ct < 2; ++ct)
      #pragma unroll
      for (int i = 0; i < 4; ++i)
        MoeS[(rt * 16 + quad * 4 + i) * 256 + wave * 32 + ct * 16 + m16] = macc[rt][ct][i];
  __syncthreads();

  float mv[16];
  float ss = 0.f;
  #pragma unroll
  for (int j = 0; j < 16; ++j) {
    mv[j] = MoeS[prow * 256 + pcol + j];
    ss += mv[j] * mv[j];
  }
  #pragma unroll
  for (int o = 8; o > 0; o >>= 1) ss += __shfl_xor(ss, o);
  const float r1 = rsqrtf(ss * (1.f / 256.f) + kEPS);
  float ss2 = 0.f;
  #pragma unroll
  for (int j = 0; j < 16; ++j) {
    hv[j] += wf[pcol + j] * mv[j] * r1;
    ss2 += hv[j] * hv[j];
  }
  #pragma unroll
  for (int o = 8; o > 0; o >>= 1) ss2 += __shfl_xor(ss2, o);
  const float r2 = rsqrtf(ss2 * (1.f / 256.f) + kEPS);

  const size_t base = (size_t)(r0 + prow) * 256 + pcol;
  #pragma unroll
  for (int j = 0; j < 16; j += 4)
    *(float4*)(h + base + j) = float4{hv[j], hv[j + 1], hv[j + 2], hv[j + 3]};
  #pragma unroll
  for (int j = 0; j < 16; j += 4) {
    *(ushort4*)(hb2 + base + j) = make_ushort4(f2b(hv[j]), f2b(hv[j + 1]), f2b(hv[j + 2]), f2b(hv[j + 3]));
    *(ushort4*)(hn + base + j) = make_ushort4(
        f2b(wa[pcol + j] * hv[j] * r2), f2b(wa[pcol + j + 1] * hv[j + 1] * r2),
        f2b(wa[pcol + j + 2] * hv[j + 2] * r2), f2b(wa[pcol + j + 3] * hv[j + 3] * r2));
  }
}

// ---------------- block-wide sum over 256 threads ----------------
__device__ __forceinline__ float block_sum256(float v) {
  #pragma unroll
  for (int o = 32; o > 0; o >>= 1) v += __shfl_down(v, o);
  __shared__ float red[4];
  __syncthreads();
  if ((threadIdx.x & 63) == 0) red[threadIdx.x >> 6] = v;
  __syncthreads();
  return red[0] + red[1] + red[2] + red[3];
}

__global__ __launch_bounds__(256) void rms_a_k(const float* __restrict__ h, const float* __restrict__ w,
                                               u16* __restrict__ hn) {
  const int l = blockIdx.x, t = threadIdx.x;
  const float v = h[(size_t)l * kDIM + t];
  const float ssum = block_sum256(v * v);
  const float r = rsqrtf(ssum * (1.f / 256.f) + kEPS);
  hn[(size_t)l * kDIM + t] = f2b(w[t] * v * r);
}

// causal depthwise conv (4 taps, 4 channels/thread) + bias + silu -> xcb; z*silu(z) -> zsb;
// also zeroes xdbl for the split-K atomic GEMM that follows.
__global__ __launch_bounds__(256) void conv_silu_k(const u16* __restrict__ xz, const float* __restrict__ cw,
                                                   const float* __restrict__ cb,
                                                   u16* __restrict__ xcb, u16* __restrict__ zsb,
                                                   float* __restrict__ xdbl) {
  const int i4 = blockIdx.x * 256 + threadIdx.x;  // L*DI/4
  if (i4 < 98304) *(float4*)&xdbl[i4 * 4] = float4{0.f, 0.f, 0.f, 0.f};
  const int l = i4 >> 7;
  const int d = (i4 & 127) * 4;
  float acc[4];
  const float4 cbv = *(const float4*)&cb[d];
  acc[0] = cbv.x; acc[1] = cbv.y; acc[2] = cbv.z; acc[3] = cbv.w;
  #pragma unroll
  for (int j = 0; j < 4; ++j) {
    const int ll = l - 3 + j;
    if (ll >= 0) {
      const ushort4 xv = *(const ushort4*)&xz[(size_t)ll * 1024 + d];
      acc[0] += cw[(d + 0) * 4 + j] * b2f(xv.x);
      acc[1] += cw[(d + 1) * 4 + j] * b2f(xv.y);
      acc[2] += cw[(d + 2) * 4 + j] * b2f(xv.z);
      acc[3] += cw[(d + 3) * 4 + j] * b2f(xv.w);
    }
  }
  ushort4 xo, zo;
  const ushort4 zv = *(const ushort4*)&xz[(size_t)l * 1024 + 512 + d];
  float z0 = b2f(zv.x), z1 = b2f(zv.y), z2 = b2f(zv.z), z3 = b2f(zv.w);
  xo.x = f2b(acc[0] * sigm(acc[0])); xo.y = f2b(acc[1] * sigm(acc[1]));
  xo.z = f2b(acc[2] * sigm(acc[2])); xo.w = f2b(acc[3] * sigm(acc[3]));
  zo.x = f2b(z0 * sigm(z0)); zo.y = f2b(z1 * sigm(z1));
  zo.z = f2b(z2 * sigm(z2)); zo.w = f2b(z3 * sigm(z3));
  *(ushort4*)&xcb[(size_t)l * 512 + d] = xo;
  *(ushort4*)&zsb[(size_t)l * 512 + d] = zo;
}

// ---------------- chunked selective scan; lane-pair state split ----------------
__global__ __launch_bounds__(256) void scan_a_k(const float* __restrict__ xdbl, const u16* __restrict__ xcb,
                                                const float* __restrict__ A_log, const float* __restrict__ dtw,
                                                const float* __restrict__ dtb,
                                                u16* __restrict__ delta,
                                                float* __restrict__ aprod, float* __restrict__ bacc) {
  const int c = blockIdx.x;
  const int t = threadIdx.x;
  const int half = t & 1;
  const int d = blockIdx.y * 128 + (t >> 1);
  const int l0 = c * 64;
  __shared__ float Xs[64][32];  // [lr][0:16)=dr, [16:32)=B
  for (int i = t; i < 2048; i += 256)
    Xs[i >> 5][i & 31] = xdbl[(size_t)(l0 + (i >> 5)) * 48 + (i & 31)];
  __syncthreads();
  float wd[8], Ad[8];
  #pragma unroll
  for (int j = 0; j < 8; ++j) wd[j] = dtw[d * 16 + half * 8 + j];
  const float bd = dtb[d];
  #pragma unroll
  for (int n = 0; n < 8; ++n) Ad[n] = -__expf(A_log[d * 16 + half * 8 + n]);
  float s[8], ap[8];
  #pragma unroll
  for (int n = 0; n < 8; ++n) { s[n] = 0.f; ap[n] = 1.f; }
  #pragma unroll 4
  for (int lr = 0; lr < 64; ++lr) {
    const float4 dr0 = *(const float4*)&Xs[lr][half * 8];
    const float4 dr1 = *(const float4*)&Xs[lr][half * 8 + 4];
    float p0 = dr0.x * wd[0] + dr0.y * wd[1] + dr0.z * wd[2] + dr0.w * wd[3];
    float p1 = dr1.x * wd[4] + dr1.y * wd[5] + dr1.z * wd[6] + dr1.w * wd[7];
    float dot = p0 + p1;
    dot += __shfl_xor(dot, 1);
    const float dl = softplus_fast(dot + bd);
    const int l = l0 + lr;
    if (!half) delta[(size_t)l * 512 + d] = f2b(dl);
    const float du = dl * b2f(xcb[(size_t)l * 512 + d]);
    const float4 B0 = *(const float4*)&Xs[lr][16 + half * 8];
    const float4 B1 = *(const float4*)&Xs[lr][16 + half * 8 + 4];
    const float Bv[8] = {B0.x, B0.y, B0.z, B0.w, B1.x, B1.y, B1.z, B1.w};
    #pragma unroll
    for (int n = 0; n < 8; ++n) {
      const float a = __expf(dl * Ad[n]);
      s[n] = fmaf(a, s[n], du * Bv[n]);
      ap[n] *= a;
    }
  }
  const int base = c * 8192 + d * 16 + half * 8;
  #pragma unroll
  for (int n = 0; n < 8; ++n) { aprod[base + n] = ap[n]; bacc[base + n] = s[n]; }
}

// chunk combine (32 blocks, 128 serial iters, software prefetch)
__global__ __launch_bounds__(256) void scan_b_k(const float* __restrict__ aprod, const float* __restrict__ bacc,
                                                float* __restrict__ sinit) {
  const int st = blockIdx.x * 256 + threadIdx.x;  // 8192 states
  float cur = 0.f;
  float a0 = aprod[st], b0 = bacc[st];
  for (int c = 0; c < 128; ++c) {
    float a1 = 0.f, b1 = 0.f;
    if (c + 1 < 128) {
      a1 = aprod[(size_t)(c + 1) * 8192 + st];
      b1 = bacc[(size_t)(c + 1) * 8192 + st];
    }
    sinit[(size_t)c * 8192 + st] = cur;
    cur = fmaf(a0, cur, b0);
    a0 = a1; b0 = b1;
  }
}

__global__ __launch_bounds__(256) void scan_c_k(const float* __restrict__ xdbl, const u16* __restrict__ xcb,
                                                const u16* __restrict__ zsb, const float* __restrict__ A_log,
                                                const u16* __restrict__ delta,
                                                const float* __restrict__ sinit,
                                                const float* __restrict__ Dp, u16* __restrict__ yv) {
  const int c = blockIdx.x;
  const int t = threadIdx.x;
  const int half = t & 1;
  const int d = blockIdx.y * 128 + (t >> 1);
  const int l0 = c * 64;
  __shared__ float Xs[64][32];  // [lr][0:16)=B, [16:32)=C
  for (int i = t; i < 2048; i += 256)
    Xs[i >> 5][i & 31] = xdbl[(size_t)(l0 + (i >> 5)) * 48 + 16 + (i & 31)];
  __syncthreads();
  float Ad[8];
  #pragma unroll
  for (int n = 0; n < 8; ++n) Ad[n] = -__expf(A_log[d * 16 + half * 8 + n]);
  float s[8];
  const int base = c * 8192 + d * 16 + half * 8;
  #pragma unroll
  for (int n = 0; n < 8; ++n) s[n] = sinit[base + n];
  const float Dd = Dp[d];
  #pragma unroll 4
  for (int lr = 0; lr < 64; ++lr) {
    const int l = l0 + lr;
    const float dl = b2f(delta[(size_t)l * 512 + d]);
    const float xv = b2f(xcb[(size_t)l * 512 + d]);
    const float zs = b2f(zsb[(size_t)l * 512 + d]);
    const float du = dl * xv;
    const float4 B0 = *(const float4*)&Xs[lr][half * 8];
    const float4 B1 = *(const float4*)&Xs[lr][half * 8 + 4];
    const float4 C0 = *(const float4*)&Xs[lr][16 + half * 8];
    const float4 C1 = *(const float4*)&Xs[lr][16 + half * 8 + 4];
    const float Bv[8] = {B0.x, B0.y, B0.z, B0.w, B1.x, B1.y, B1.z, B1.w};
    const float Cv[8] = {C0.x, C0.y, C0.z, C0.w, C1.x, C1.y, C1.z, C1.w};
    float y = 0.f;
    #pragma unroll
    for (int n = 0; n < 8; ++n) {
      const float a = __expf(dl * Ad[n]);
      s[n] = fmaf(a, s[n], du * Bv[n]);
      y = fmaf(s[n], Cv[n], y);
    }
    y += __shfl_xor(y, 1);
    if (!half) yv[(size_t)l * 512 + d] = f2b((y + xv * Dd) * zs);
  }
}

extern "C" void kernel_launch(void* const* d_in, const int* in_sizes, int n_in,
                              void* d_out, int out_size, void* d_ws, size_t ws_size,
                              hipStream_t stream) {
  const float* x        = (const float*)d_in[0];
  const float* lin_w    = (const float*)d_in[1];
  const float* in_proj  = (const float*)d_in[2];
  const float* conv_w   = (const float*)d_in[3];
  const float* conv_b   = (const float*)d_in[4];
  const float* x_proj   = (const float*)d_in[5];
  const float* dt_w     = (const float*)d_in[6];
  const float* dt_b     = (const float*)d_in[7];
  const float* A_log    = (const float*)d_in[8];
  const float* D_param  = (const float*)d_in[9];
  const float* out_proj = (const float*)d_in[10];
  const float* gate_w   = (const float*)d_in[11];
  const float* gproj    = (const float*)d_in[12];
  const float* uproj    = (const float*)d_in[13];
  const float* dproj    = (const float*)d_in[14];
  const float* rms_a_w  = (const float*)d_in[15];
  const float* rms_f_w  = (const float*)d_in[16];
  const float* head_w1  = (const float*)d_in[17];
  const float* head_w2  = (const float*)d_in[18];

  char* p = (char*)d_ws;
  auto alloc = [&](size_t bytes) -> char* {
    char* r = p;
    p += (bytes + 255) & ~(size_t)255;
    return r;
  };

  // bf16 weight pool
  u16* lin_b  = (u16*)alloc(65536 * 2);
  u16* ipw_b  = (u16*)alloc((size_t)2097152 * 2);
  u16* xpw_b  = (u16*)alloc((size_t)196608 * 2);
  u16* opw_b  = (u16*)alloc((size_t)1048576 * 2);
  u16* gupw_b = (u16*)alloc((size_t)8388608 * 2);  // 16-wide gu interleave, expert-grouped
  u16* dpw_b  = (u16*)alloc((size_t)4194304 * 2);
  u16* hw1_b  = (u16*)alloc(65536 * 2);
  u16* hw2_b  = (u16*)alloc(8192 * 2);

  // activations
  u16* xT     = (u16*)alloc((size_t)kL * kDIM * 2);
  float* h    = (float*)alloc((size_t)kL * kDIM * 4);
  u16* hn     = (u16*)alloc((size_t)kL * kDIM * 2);
  u16* hb2    = (u16*)alloc((size_t)kL * kDIM * 2);
  float* xdbl = (float*)alloc((size_t)kL * 48 * 4);
  u16* fb     = (u16*)alloc((size_t)kL * kDIM * 2);
  u16* h2b    = (u16*)alloc((size_t)kL * kDIM * 2);
  u16* xz     = (u16*)alloc((size_t)kL * 1024 * 2);
  u16* xcb    = (u16*)alloc((size_t)kL * kDI * 2);
  u16* zsb    = (u16*)alloc((size_t)kL * kDI * 2);
  u16* yv     = (u16*)alloc((size_t)kL * kDI * 2);
  u16* delta  = (u16*)alloc((size_t)kL * kDI * 2);
  float* aprod = (float*)alloc((size_t)128 * 8192 * 4);
  float* bacc  = (float*)alloc((size_t)128 * 8192 * 4);
  float* sinit = (float*)alloc((size_t)128 * 8192 * 4);
  float* hpart = (float*)alloc((size_t)4 * kL * kDIM * 4);

  if ((size_t)(p - (char*)d_ws) > ws_size) return;  // fail loudly

  // ---- weight conversion ----
  Cvt2 dd;
  int seg = 0, blk = 0;
  auto add = [&](const float* s, u16* d, int n, int mode) {
    dd.s[seg] = s; dd.d[seg] = d; dd.n[seg] = n; dd.mode[seg] = mode;
    dd.bstart[seg] = blk;
    blk += (n + 4095) / 4096;
    ++seg;
  };
  add(lin_w, lin_b, 65536, 0);
  add(in_proj, ipw_b, 2097152, 0);
  add(x_proj, xpw_b, 196608, 0);
  add(out_proj, opw_b, 1048576, 0);
  add(head_w1, hw1_b, 65536, 0);
  add(head_w2, hw2_b, 8192, 0);
  for (int i = 0; i < kNB; ++i) {
    add(gproj + (size_t)i * 524288, gupw_b + (size_t)i * 1048576, 524288, 1);
    add(uproj + (size_t)i * 524288, gupw_b + (size_t)i * 1048576 + 4096, 524288, 1);
  }
  add(dproj, dpw_b, 4194304, 2);
  dd.nseg = seg;
  dd.bstart[seg] = blk;
  cvt2_k<<<blk, 256, 0, stream>>>(dd);
  transpose_x_k<<<dim3(kL / 32, kDIM / 32), dim3(32, 8), 0, stream>>>(x, xT);

  // h = xT @ lin_w^T
  gemm_t<64, 128, 2, 4, 2, 0><<<dim3(128, 2, 1), 256, 0, stream>>>(
      xT, 256, lin_b, 256, h, 256, 256, 256, 0);
  rms_a_k<<<kL, 256, 0, stream>>>(h, rms_a_w, hn);

  for (int i = 0; i < kNB; ++i) {
    // in_proj: N=1024, K=256 -> xz bf16
    gemm_t<128, 128, 4, 4, 2, 2><<<dim3(64, 8, 1), 256, 0, stream>>>(
        hn, 256, ipw_b + (size_t)i * 262144, 256, xz, 1024, 1024, 256, 0);
    conv_silu_k<<<kL * kDI / 1024, 256, 0, stream>>>(xz, conv_w + (size_t)i * 2048,
                                                     conv_b + (size_t)i * 512, xcb, zsb, xdbl);
    // xdbl: N=48, K=512, split-K=8 atomic (xdbl zeroed by conv kernel)
    gemm_t<128, 48, 2, 3, 1, 4><<<dim3(64, 1, 8), 256, 0, stream>>>(
        xcb, 512, xpw_b + (size_t)i * 24576, 512, xdbl, 48, 48, 512, 0);
    scan_a_k<<<dim3(128, 4), 256, 0, stream>>>(xdbl, xcb, A_log + (size_t)i * 8192,
                                               dt_w + (size_t)i * 8192, dt_b + (size_t)i * 512,
                                               delta, aprod, bacc);
    scan_b_k<<<32, 256, 0, stream>>>(aprod, bacc, sinit);
    scan_c_k<<<dim3(128, 4), 256, 0, stream>>>(xdbl, xcb, zsb, A_log + (size_t)i * 8192,
                                               delta, sinit, D_param + (size_t)i * 512, yv);
    // out_proj: split-K=4 -> 4 partial buffers (reduced in mega)
    gemm_t<128, 128, 4, 4, 2, 5><<<dim3(64, 2, 4), 256, 0, stream>>>(
        yv, 512, opw_b + (size_t)i * 131072, 512, hpart, 256, 256, 512, 2097152);
    // fused MoE (router + gu + GLU + dproj + rms_f + rms_a), barrier-light
    moe_mega_k<<<256, 512, 0, stream>>>(h, hpart, gate_w + (size_t)i * 1024,
                                        gupw_b + (size_t)i * 1048576, dpw_b + (size_t)i * 524288,
                                        rms_f_w, rms_a_w, hb2, hn);
  }

  // head: lin -> silu(head1) -> head2 + sigmoid-transpose fused
  gemm_t<64, 128, 2, 4, 2, 2><<<dim3(128, 2, 1), 256, 0, stream>>>(
      hb2, 256, lin_b, 256, h2b, 256, 256, 256, 0);
  gemm_t<64, 128, 2, 4, 2, 3><<<dim3(128, 2, 1), 256, 0, stream>>>(
      h2b, 256, hw1_b, 256, fb, 256, 256, 256, 0);
  gemm_t<64, 128, 2, 4, 2, 7><<<dim3(128, 1, 1), 256, 0, stream>>>(
      fb, 256, hw2_b, 256, (float*)d_out, 32, 32, 256, 0);
}

// Round 7
// 2007.601 us; speedup vs baseline: 1.4124x; 1.4124x over previous
//
#include <hip/hip_runtime.h>

typedef unsigned short u16;
typedef unsigned int u32;
using bf16x8 = __attribute__((ext_vector_type(8))) short;
using f32x4 = __attribute__((ext_vector_type(4))) float;

constexpr int kL = 8192;
constexpr int kDIM = 256;
constexpr int kDI = 512;
constexpr int kNB = 8;
constexpr float kEPS = 1e-3f;

__device__ __forceinline__ u16 f2b(float f) {
  u32 x = __builtin_bit_cast(u32, f);
  x += 0x7fffu + ((x >> 16) & 1u);
  return (u16)(x >> 16);
}
__device__ __forceinline__ float b2f(u16 u) {
  return __builtin_bit_cast(float, (u32)u << 16);
}
__device__ __forceinline__ float sigm(float x) { return 1.f / (1.f + __expf(-x)); }
__device__ __forceinline__ float softplus_fast(float x) {
  return fmaxf(x, 0.f) + __logf(1.f + __expf(-fabsf(x)));
}

__device__ __forceinline__ void async_cp16(const void* g, void* l) {
  __builtin_amdgcn_global_load_lds((const __attribute__((address_space(1))) u32*)g,
                                   (__attribute__((address_space(3))) u32*)l, 16, 0, 0);
}

// ---------------- balanced vectorized weight conversion ----------------
// mode 0: identity.
// mode 1: gu 16-wide interleave with expert grouping:
//   src row (e*512 + j) -> dst row e*1024 + (j>>4)*32 + (j&15)  (u: dst ptr pre-offset +16 rows)
// mode 2: dproj permute (NB,NE,DIM,INNER) -> (NB, DIM, NE*INNER).
struct Cvt2 {
  const float* s[23];
  u16* d[23];
  int n[23];
  int mode[23];
  int bstart[24];
  int nseg;
};
__global__ __launch_bounds__(256) void cvt2_k(Cvt2 dd) {
  const int b = blockIdx.x;
  int seg = 0;
  for (int i = 1; i < dd.nseg; ++i) seg += (b >= dd.bstart[i]) ? 1 : 0;
  const int lb = b - dd.bstart[seg];
  const float* s = dd.s[seg];
  u16* d = dd.d[seg];
  const int n = dd.n[seg];
  const int mode = dd.mode[seg];
  #pragma unroll
  for (int it = 0; it < 4; ++it) {
    const int e4 = lb * 1024 + it * 256 + threadIdx.x;
    const int i = e4 * 4;
    if (i >= n) break;
    const float4 v = ((const float4*)s)[e4];
    ushort4 o = make_ushort4(f2b(v.x), f2b(v.y), f2b(v.z), f2b(v.w));
    size_t dst;
    if (mode == 0) {
      dst = (size_t)i;
    } else if (mode == 1) {
      const int row = i >> 8, col = i & 255;
      const int drow = (row >> 9) * 1024 + ((row >> 4) & 31) * 32 + (row & 15);
      dst = (size_t)drow * 256 + col;
    } else {
      const int bb = i >> 19, e = (i >> 17) & 3, nr = (i >> 9) & 255, j = i & 511;
      dst = (size_t)bb * 524288 + (size_t)nr * 2048 + e * 512 + j;
    }
    *(ushort4*)&d[dst] = o;
  }
}

// x (DIM, L) f32 -> xT (L, DIM) bf16
__global__ __launch_bounds__(256) void transpose_x_k(const float* __restrict__ x, u16* __restrict__ xT) {
  __shared__ float tile[32][33];
  int l0 = blockIdx.x * 32, d0 = blockIdx.y * 32;
  int tx = threadIdx.x, ty = threadIdx.y;
  #pragma unroll
  for (int i = 0; i < 32; i += 8)
    tile[ty + i][tx] = x[(size_t)(d0 + ty + i) * kL + l0 + tx];
  __syncthreads();
  #pragma unroll
  for (int i = 0; i < 32; i += 8)
    xT[(size_t)(l0 + ty + i) * kDIM + d0 + tx] = f2b(tile[tx][ty + i]);
}

// ---------------- templated MFMA GEMM: C(MxN) = A(MxK) @ W(NxK)^T ----------------
// MODE 0: f32 store; 2: bf16 store; 3: silu->bf16; 4: f32 atomicAdd (split-K);
// MODE 5: f32 partial store at C + blockIdx.z*pstride; MODE 7: sigmoid + transposed store.
// Staging addresses hoisted out of the K-loop (pointer bump, no per-iter addr math).
template <int BM, int BN, int TR, int TC, int WCN, int MODE>
__global__ __launch_bounds__(256) void gemm_t(
    const u16* __restrict__ A, int lda,
    const u16* __restrict__ W, int ldw,
    void* __restrict__ C, int ldc,
    int N, int K, int pstride)
{
  constexpr int BNR = (BN + 63) & ~63;
  constexpr int NA = BM * 64 / 2048;
  constexpr int NBt = BNR * 64 / 2048;
  __shared__ u16 As[BM * 64];
  __shared__ u16 Bs[BNR * 64];
  const int tid = threadIdx.x;
  const int lane = tid & 63;
  const int wave = tid >> 6;
  const int bm = blockIdx.x * BM;
  const int bn = blockIdx.y * BN;
  const int wrow = (wave / WCN) * (TR * 16);
  const int wcol = (wave % WCN) * (TC * 16);
  const int kchunk = K / (int)gridDim.z;
  const int kbeg = blockIdx.z * kchunk;
  const int niter = kchunk >> 6;

  // hoisted staging addresses
  const u16* aSrc[NA];
  int aDst[NA];
  #pragma unroll
  for (int it = 0; it < NA; ++it) {
    const int flat = (it * 256 + tid) * 8;
    const int r = flat >> 6;
    const int gc = ((((flat >> 3) & 7) ^ (r & 7)) << 3);
    aDst[it] = flat;
    aSrc[it] = A + (size_t)(bm + r) * lda + kbeg + gc;
  }
  const u16* bSrc[NBt];
  int bDst[NBt];
  #pragma unroll
  for (int it = 0; it < NBt; ++it) {
    const int flat = (it * 256 + tid) * 8;
    const int r = flat >> 6;
    const int gc = ((((flat >> 3) & 7) ^ (r & 7)) << 3);
    int n = bn + r;
    if (n > N - 1) n = N - 1;
    bDst[it] = flat;
    bSrc[it] = W + (size_t)n * ldw + kbeg + gc;
  }

  f32x4 acc[TR][TC];
  #pragma unroll
  for (int r = 0; r < TR; ++r)
    #pragma unroll
    for (int c = 0; c < TC; ++c)
      acc[r][c] = f32x4{0.f, 0.f, 0.f, 0.f};

  for (int ki = 0; ki < niter; ++ki) {
    #pragma unroll
    for (int it = 0; it < NA; ++it) {
      async_cp16(aSrc[it], &As[aDst[it]]);
      aSrc[it] += 64;
    }
    #pragma unroll
    for (int it = 0; it < NBt; ++it) {
      async_cp16(bSrc[it], &Bs[bDst[it]]);
      bSrc[it] += 64;
    }
    __syncthreads();
    #pragma unroll
    for (int kk = 0; kk < 64; kk += 32) {
      const int kc = (kk >> 3) + (lane >> 4);
      const int mrow = lane & 15;
      bf16x8 a[TR], b[TC];
      #pragma unroll
      for (int rr = 0; rr < TR; ++rr) {
        int row = wrow + rr * 16 + mrow;
        a[rr] = *(const bf16x8*)&As[row * 64 + ((kc ^ (row & 7)) << 3)];
      }
      #pragma unroll
      for (int cc = 0; cc < TC; ++cc) {
        int row = wcol + cc * 16 + mrow;
        b[cc] = *(const bf16x8*)&Bs[row * 64 + ((kc ^ (row & 7)) << 3)];
      }
      #pragma unroll
      for (int rr = 0; rr < TR; ++rr)
        #pragma unroll
        for (int cc = 0; cc < TC; ++cc)
          acc[rr][cc] = __builtin_amdgcn_mfma_f32_16x16x32_bf16(a[rr], b[cc], acc[rr][cc], 0, 0, 0);
    }
    __syncthreads();
  }

  const int colb = bn + wcol + (lane & 15);
  const int rowb = bm + wrow + ((lane >> 4) << 2);
  #pragma unroll
  for (int rr = 0; rr < TR; ++rr)
    #pragma unroll
    for (int cc = 0; cc < TC; ++cc) {
      int col = colb + cc * 16;
      if (col >= N) continue;
      #pragma unroll
      for (int i = 0; i < 4; ++i) {
        const int row = rowb + rr * 16 + i;
        size_t off = (size_t)row * ldc + col;
        float v = acc[rr][cc][i];
        if constexpr (MODE == 0) ((float*)C)[off] = v;
        else if constexpr (MODE == 2) ((u16*)C)[off] = f2b(v);
        else if constexpr (MODE == 3) ((u16*)C)[off] = f2b(v * sigm(v));
        else if constexpr (MODE == 4) atomicAdd(&((float*)C)[off], v);
        else if constexpr (MODE == 5) ((float*)C)[off + (size_t)blockIdx.z * pstride] = v;
        else if constexpr (MODE == 7) ((float*)C)[(size_t)col * kL + row] = sigm(v);
      }
    }
}

// ---------------- fused MoE mega-kernel (round-5 proven structure) ----------------
// 256 blocks x 512 threads, 32 rows of h per block. LDS-staged weights (double-buffered).
__global__ __launch_bounds__(512, 1) void moe_mega_k(
    float* __restrict__ h, const float* __restrict__ hpart,
    const float* __restrict__ gw,
    const u16* __restrict__ Wgu, const u16* __restrict__ Wd,
    const float* __restrict__ wf, const float* __restrict__ wa,
    u16* __restrict__ hb2, u16* __restrict__ hn)
{
  __shared__ u16 Ah[32 * 256];       // 16 KB, swizzled 16B chunks: chunk ^ (row&7)
  __shared__ u16 Ts[32 * 512];       // 32 KB, swizzled
  __shared__ u16 Ws[2][256 * 64];    // 64 KB staging, swizzled
  __shared__ float WeS[32][4];
  const int tid = threadIdx.x;
  const int lane = tid & 63;
  const int quad = lane >> 4;
  const int m16 = lane & 15;
  const int wave = tid >> 6;         // 0..7
  const int wcol = wave * 32;
  const int r0 = blockIdx.x * 32;
  const int prow = tid >> 4;         // 0..31
  const int pcol = (tid & 15) * 16;

  // ---- phase -1 ----
  float hv[16];
  {
    const size_t base = (size_t)(r0 + prow) * 256 + pcol;
    #pragma unroll
    for (int j = 0; j < 16; j += 4) {
      float4 v = *(const float4*)(h + base + j);
      #pragma unroll
      for (int z = 0; z < 2; ++z) {
        const float4 pv = *(const float4*)(hpart + (size_t)z * 2097152 + base + j);
        v.x += pv.x; v.y += pv.y; v.z += pv.z; v.w += pv.w;
      }
      hv[j] = v.x; hv[j + 1] = v.y; hv[j + 2] = v.z; hv[j + 3] = v.w;
    }
  }
  {
    float p[4];
    #pragma unroll
    for (int e = 0; e < 4; ++e) {
      float s = 0.f;
      #pragma unroll
      for (int j = 0; j < 16; ++j) s += hv[j] * gw[e * 256 + pcol + j];
      p[e] = s;
    }
    #pragma unroll
    for (int o = 8; o > 0; o >>= 1) {
      p[0] += __shfl_xor(p[0], o); p[1] += __shfl_xor(p[1], o);
      p[2] += __shfl_xor(p[2], o); p[3] += __shfl_xor(p[3], o);
    }
    if ((tid & 15) == 0) {
      int i0 = 0;
      #pragma unroll
      for (int e = 1; e < 4; ++e) if (p[e] > p[i0]) i0 = e;
      int i1 = -1;
      #pragma unroll
      for (int e = 0; e < 4; ++e) {
        if (e == i0) continue;
        if (i1 < 0 || p[e] > p[i1]) i1 = e;
      }
      const float tt = __expf(p[i1] - p[i0]);
      float o0 = 1.f / (1.f + tt), o1 = tt / (1.f + tt);
      WeS[prow][0] = 0.f; WeS[prow][1] = 0.f; WeS[prow][2] = 0.f; WeS[prow][3] = 0.f;
      WeS[prow][i0] = o0; WeS[prow][i1] = o1;
    }
    // Ah store (swizzled)
    #pragma unroll
    for (int cc = 0; cc < 2; ++cc) {
      const int chunk = (pcol >> 3) + cc;
      const int sw = ((chunk ^ (prow & 7)) << 3);
      u16 tmp[8];
      #pragma unroll
      for (int j = 0; j < 8; ++j) tmp[j] = f2b(hv[cc * 8 + j]);
      *(bf16x8*)&Ah[prow * 256 + sw] = *(bf16x8*)tmp;
    }
  }
  __syncthreads();

  f32x4 macc[2][2];
  #pragma unroll
  for (int rt = 0; rt < 2; ++rt)
    #pragma unroll
    for (int ct = 0; ct < 2; ++ct) macc[rt][ct] = f32x4{0.f, 0.f, 0.f, 0.f};

  auto stage_gu = [&](int buf, int e, int nc, int k0) {
    #pragma unroll
    for (int it = 0; it < 4; ++it) {
      const int flat = (it * 512 + tid) * 8;
      const int r = flat >> 6;
      const int gc = ((((flat >> 3) & 7) ^ (r & 7)) << 3);
      async_cp16(Wgu + (size_t)(e * 1024 + nc * 256 + r) * 256 + k0 + gc, &Ws[buf][flat]);
    }
  };
  auto stage_dp = [&](int buf, int e, int k0) {
    #pragma unroll
    for (int it = 0; it < 4; ++it) {
      const int flat = (it * 512 + tid) * 8;
      const int r = flat >> 6;
      const int gc = ((((flat >> 3) & 7) ^ (r & 7)) << 3);
      async_cp16(Wd + (size_t)r * 2048 + e * 512 + k0 + gc, &Ws[buf][flat]);
    }
  };

  for (int e = 0; e < 4; ++e) {
    // ---- phase 1 ----
    for (int nc = 0; nc < 4; ++nc) {
      f32x4 acc[2][2];
      #pragma unroll
      for (int rt = 0; rt < 2; ++rt)
        #pragma unroll
        for (int ct = 0; ct < 2; ++ct) acc[rt][ct] = f32x4{0.f, 0.f, 0.f, 0.f};
      stage_gu(0, e, nc, 0);
      __syncthreads();
      #pragma unroll
      for (int k0i = 0; k0i < 4; ++k0i) {
        if (k0i < 3) stage_gu((k0i + 1) & 1, e, nc, (k0i + 1) * 64);
        const u16* buf = Ws[k0i & 1];
        #pragma unroll
        for (int kk = 0; kk < 64; kk += 32) {
          const int kcs = (kk >> 3) + quad;
          bf16x8 a[2], b[2];
          #pragma unroll
          for (int rt = 0; rt < 2; ++rt) {
            const int row = rt * 16 + m16;
            const int ch = ((k0i * 64 + kk) >> 3) + quad;
            a[rt] = *(const bf16x8*)&Ah[row * 256 + ((ch ^ (row & 7)) << 3)];
          }
          #pragma unroll
          for (int ct = 0; ct < 2; ++ct) {
            const int n = wcol + ct * 16 + m16;
            b[ct] = *(const bf16x8*)&buf[n * 64 + ((kcs ^ (n & 7)) << 3)];
          }
          #pragma unroll
          for (int rt = 0; rt < 2; ++rt)
            #pragma unroll
            for (int ct = 0; ct < 2; ++ct)
              acc[rt][ct] = __builtin_amdgcn_mfma_f32_16x16x32_bf16(a[rt], b[ct], acc[rt][ct], 0, 0, 0);
        }
        __syncthreads();
      }
      // GLU mix -> Ts (g = acc[rt][0], u = acc[rt][1]; same lane holds the pair)
      const int group = nc * 8 + wave;
      const int j = group * 16 + m16;
      #pragma unroll
      for (int rt = 0; rt < 2; ++rt)
        #pragma unroll
        for (int i = 0; i < 4; ++i) {
          const int row = rt * 16 + quad * 4 + i;
          const float g = acc[rt][0][i];
          const float u = acc[rt][1][i];
          const float val = g * sigm(g) * u * WeS[row][e];
          Ts[row * 512 + (((j >> 3) ^ (row & 7)) << 3) + (j & 7)] = f2b(val);
        }
    }
    __syncthreads();  // Ts complete
    // ---- phase 2 ----
    stage_dp(0, e, 0);
    __syncthreads();
    #pragma unroll
    for (int k0i = 0; k0i < 8; ++k0i) {
      if (k0i < 7) stage_dp((k0i + 1) & 1, e, (k0i + 1) * 64);
      const u16* buf = Ws[k0i & 1];
      #pragma unroll
      for (int kk = 0; kk < 64; kk += 32) {
        const int kcs = (kk >> 3) + quad;
        bf16x8 a[2], b[2];
        #pragma unroll
        for (int rt = 0; rt < 2; ++rt) {
          const int row = rt * 16 + m16;
          const int ch = ((k0i * 64 + kk) >> 3) + quad;
          a[rt] = *(const bf16x8*)&Ts[row * 512 + ((ch ^ (row & 7)) << 3)];
        }
        #pragma unroll
        for (int ct = 0; ct < 2; ++ct) {
          const int n = wcol + ct * 16 + m16;
          b[ct] = *(const bf16x8*)&buf[n * 64 + ((kcs ^ (n & 7)) << 3)];
        }
        #pragma unroll
        for (int rt = 0; rt < 2; ++rt)
          #pragma unroll
          for (int ct = 0; ct < 2; ++ct)
            macc[rt][ct] = __builtin_amdgcn_mfma_f32_16x16x32_bf16(a[rt], b[ct], macc[rt][ct], 0, 0, 0);
      }
      __syncthreads();
    }
  }

  // ---- epilogue: macc -> LDS (row-major f32 overlay on Ts), dual rmsnorm, stores ----
  float* MoeS = (float*)Ts;  // 32x256 f32 = 32 KB
  __syncthreads();
  #pragma unroll
  for (int rt = 0; rt < 2; ++rt)
    #pragma unroll
    for (int ct = 0; ct < 2; ++ct)
      #pragma unroll
      for (int i = 0; i < 4; ++i)
        MoeS[(rt * 16 + quad * 4 + i) * 256 + wcol + ct * 16 + m16] = macc[rt][ct][i];
  __syncthreads();

  float mv[16];
  float ss = 0.f;
  #pragma unroll
  for (int j = 0; j < 16; ++j) {
    mv[j] = MoeS[prow * 256 + pcol + j];
    ss += mv[j] * mv[j];
  }
  #pragma unroll
  for (int o = 8; o > 0; o >>= 1) ss += __shfl_xor(ss, o);
  const float r1 = rsqrtf(ss * (1.f / 256.f) + kEPS);
  float ss2 = 0.f;
  #pragma unroll
  for (int j = 0; j < 16; ++j) {
    hv[j] += wf[pcol + j] * mv[j] * r1;
    ss2 += hv[j] * hv[j];
  }
  #pragma unroll
  for (int o = 8; o > 0; o >>= 1) ss2 += __shfl_xor(ss2, o);
  const float r2 = rsqrtf(ss2 * (1.f / 256.f) + kEPS);

  const size_t base = (size_t)(r0 + prow) * 256 + pcol;
  #pragma unroll
  for (int j = 0; j < 16; j += 4)
    *(float4*)(h + base + j) = float4{hv[j], hv[j + 1], hv[j + 2], hv[j + 3]};
  #pragma unroll
  for (int j = 0; j < 16; j += 4) {
    *(ushort4*)(hb2 + base + j) = make_ushort4(f2b(hv[j]), f2b(hv[j + 1]), f2b(hv[j + 2]), f2b(hv[j + 3]));
    *(ushort4*)(hn + base + j) = make_ushort4(
        f2b(wa[pcol + j] * hv[j] * r2), f2b(wa[pcol + j + 1] * hv[j + 1] * r2),
        f2b(wa[pcol + j + 2] * hv[j + 2] * r2), f2b(wa[pcol + j + 3] * hv[j + 3] * r2));
  }
}

// ---------------- block-wide sum over 256 threads ----------------
__device__ __forceinline__ float block_sum256(float v) {
  #pragma unroll
  for (int o = 32; o > 0; o >>= 1) v += __shfl_down(v, o);
  __shared__ float red[4];
  __syncthreads();
  if ((threadIdx.x & 63) == 0) red[threadIdx.x >> 6] = v;
  __syncthreads();
  return red[0] + red[1] + red[2] + red[3];
}

__global__ __launch_bounds__(256) void rms_a_k(const float* __restrict__ h, const float* __restrict__ w,
                                               u16* __restrict__ hn) {
  const int l = blockIdx.x, t = threadIdx.x;
  const float v = h[(size_t)l * kDIM + t];
  const float ssum = block_sum256(v * v);
  const float r = rsqrtf(ssum * (1.f / 256.f) + kEPS);
  hn[(size_t)l * kDIM + t] = f2b(w[t] * v * r);
}

// causal depthwise conv (4 taps, 4 channels/thread) + bias + silu -> xcb; z*silu(z) -> zsb;
// also zeroes xdbl for the split-K atomic GEMM that follows.
__global__ __launch_bounds__(256) void conv_silu_k(const u16* __restrict__ xz, const float* __restrict__ cw,
                                                   const float* __restrict__ cb,
                                                   u16* __restrict__ xcb, u16* __restrict__ zsb,
                                                   float* __restrict__ xdbl) {
  const int i4 = blockIdx.x * 256 + threadIdx.x;  // L*DI/4
  if (i4 < 98304) *(float4*)&xdbl[i4 * 4] = float4{0.f, 0.f, 0.f, 0.f};
  const int l = i4 >> 7;
  const int d = (i4 & 127) * 4;
  float acc[4];
  const float4 cbv = *(const float4*)&cb[d];
  acc[0] = cbv.x; acc[1] = cbv.y; acc[2] = cbv.z; acc[3] = cbv.w;
  #pragma unroll
  for (int j = 0; j < 4; ++j) {
    const int ll = l - 3 + j;
    if (ll >= 0) {
      const ushort4 xv = *(const ushort4*)&xz[(size_t)ll * 1024 + d];
      acc[0] += cw[(d + 0) * 4 + j] * b2f(xv.x);
      acc[1] += cw[(d + 1) * 4 + j] * b2f(xv.y);
      acc[2] += cw[(d + 2) * 4 + j] * b2f(xv.z);
      acc[3] += cw[(d + 3) * 4 + j] * b2f(xv.w);
    }
  }
  ushort4 xo, zo;
  const ushort4 zv = *(const ushort4*)&xz[(size_t)l * 1024 + 512 + d];
  float z0 = b2f(zv.x), z1 = b2f(zv.y), z2 = b2f(zv.z), z3 = b2f(zv.w);
  xo.x = f2b(acc[0] * sigm(acc[0])); xo.y = f2b(acc[1] * sigm(acc[1]));
  xo.z = f2b(acc[2] * sigm(acc[2])); xo.w = f2b(acc[3] * sigm(acc[3]));
  zo.x = f2b(z0 * sigm(z0)); zo.y = f2b(z1 * sigm(z1));
  zo.z = f2b(z2 * sigm(z2)); zo.w = f2b(z3 * sigm(z3));
  *(ushort4*)&xcb[(size_t)l * 512 + d] = xo;
  *(ushort4*)&zsb[(size_t)l * 512 + d] = zo;
}

// ---------------- chunked selective scan; lane-pair state split ----------------
__global__ __launch_bounds__(256) void scan_a_k(const float* __restrict__ xdbl, const u16* __restrict__ xcb,
                                                const float* __restrict__ A_log, const float* __restrict__ dtw,
                                                const float* __restrict__ dtb,
                                                u16* __restrict__ delta,
                                                float* __restrict__ aprod, float* __restrict__ bacc) {
  const int c = blockIdx.x;
  const int t = threadIdx.x;
  const int half = t & 1;
  const int d = blockIdx.y * 128 + (t >> 1);
  const int l0 = c * 64;
  __shared__ float Xs[64][32];  // [lr][0:16)=dr, [16:32)=B
  for (int i = t; i < 2048; i += 256)
    Xs[i >> 5][i & 31] = xdbl[(size_t)(l0 + (i >> 5)) * 48 + (i & 31)];
  __syncthreads();
  float wd[8], Ad[8];
  #pragma unroll
  for (int j = 0; j < 8; ++j) wd[j] = dtw[d * 16 + half * 8 + j];
  const float bd = dtb[d];
  #pragma unroll
  for (int n = 0; n < 8; ++n) Ad[n] = -__expf(A_log[d * 16 + half * 8 + n]);
  float s[8], ap[8];
  #pragma unroll
  for (int n = 0; n < 8; ++n) { s[n] = 0.f; ap[n] = 1.f; }
  #pragma unroll 4
  for (int lr = 0; lr < 64; ++lr) {
    const float4 dr0 = *(const float4*)&Xs[lr][half * 8];
    const float4 dr1 = *(const float4*)&Xs[lr][half * 8 + 4];
    float p0 = dr0.x * wd[0] + dr0.y * wd[1] + dr0.z * wd[2] + dr0.w * wd[3];
    float p1 = dr1.x * wd[4] + dr1.y * wd[5] + dr1.z * wd[6] + dr1.w * wd[7];
    float dot = p0 + p1;
    dot += __shfl_xor(dot, 1);
    const float dl = softplus_fast(dot + bd);
    const int l = l0 + lr;
    if (!half) delta[(size_t)l * 512 + d] = f2b(dl);
    const float du = dl * b2f(xcb[(size_t)l * 512 + d]);
    const float4 B0 = *(const float4*)&Xs[lr][16 + half * 8];
    const float4 B1 = *(const float4*)&Xs[lr][16 + half * 8 + 4];
    const float Bv[8] = {B0.x, B0.y, B0.z, B0.w, B1.x, B1.y, B1.z, B1.w};
    #pragma unroll
    for (int n = 0; n < 8; ++n) {
      const float a = __expf(dl * Ad[n]);
      s[n] = fmaf(a, s[n], du * Bv[n]);
      ap[n] *= a;
    }
  }
  const int base = c * 8192 + d * 16 + half * 8;
  #pragma unroll
  for (int n = 0; n < 8; ++n) { aprod[base + n] = ap[n]; bacc[base + n] = s[n]; }
}

// chunk combine, 3 levels: 128 chunks = 16 groups x 8
__global__ __launch_bounds__(256) void scan_b1_k(const float* __restrict__ aprod, const float* __restrict__ bacc,
                                                 float* __restrict__ gp, float* __restrict__ gb) {
  const int idx = blockIdx.x * 256 + threadIdx.x;  // 8192*16
  const int st = idx & 8191, g = idx >> 13;
  float P = 1.f, S = 0.f;
  #pragma unroll
  for (int k = 0; k < 8; ++k) {
    const int c = g * 8 + k;
    const float a = aprod[(size_t)c * 8192 + st];
    S = fmaf(a, S, bacc[(size_t)c * 8192 + st]);
    P *= a;
  }
  gp[(size_t)g * 8192 + st] = P;
  gb[(size_t)g * 8192 + st] = S;
}

__global__ __launch_bounds__(256) void scan_b2_k(const float* __restrict__ gp, const float* __restrict__ gb,
                                                 float* __restrict__ ginit) {
  const int st = blockIdx.x * 256 + threadIdx.x;  // 8192
  float cur = 0.f;
  #pragma unroll
  for (int g = 0; g < 16; ++g) {
    ginit[(size_t)g * 8192 + st] = cur;
    cur = fmaf(gp[(size_t)g * 8192 + st], cur, gb[(size_t)g * 8192 + st]);
  }
}

__global__ __launch_bounds__(256) void scan_b3_k(const float* __restrict__ aprod, const float* __restrict__ bacc,
                                                 const float* __restrict__ ginit, float* __restrict__ sinit) {
  const int idx = blockIdx.x * 256 + threadIdx.x;  // 8192*16
  const int st = idx & 8191, g = idx >> 13;
  float cur = ginit[(size_t)g * 8192 + st];
  #pragma unroll
  for (int k = 0; k < 8; ++k) {
    const int c = g * 8 + k;
    sinit[(size_t)c * 8192 + st] = cur;
    cur = fmaf(aprod[(size_t)c * 8192 + st], cur, bacc[(size_t)c * 8192 + st]);
  }
}

__global__ __launch_bounds__(256) void scan_c_k(const float* __restrict__ xdbl, const u16* __restrict__ xcb,
                                                const u16* __restrict__ zsb, const float* __restrict__ A_log,
                                                const u16* __restrict__ delta,
                                                const float* __restrict__ sinit,
                                                const float* __restrict__ Dp, u16* __restrict__ yv) {
  const int c = blockIdx.x;
  const int t = threadIdx.x;
  const int half = t & 1;
  const int d = blockIdx.y * 128 + (t >> 1);
  const int l0 = c * 64;
  __shared__ float Xs[64][32];  // [lr][0:16)=B, [16:32)=C
  for (int i = t; i < 2048; i += 256)
    Xs[i >> 5][i & 31] = xdbl[(size_t)(l0 + (i >> 5)) * 48 + 16 + (i & 31)];
  __syncthreads();
  float Ad[8];
  #pragma unroll
  for (int n = 0; n < 8; ++n) Ad[n] = -__expf(A_log[d * 16 + half * 8 + n]);
  float s[8];
  const int base = c * 8192 + d * 16 + half * 8;
  #pragma unroll
  for (int n = 0; n < 8; ++n) s[n] = sinit[base + n];
  const float Dd = Dp[d];
  #pragma unroll 4
  for (int lr = 0; lr < 64; ++lr) {
    const int l = l0 + lr;
    const float dl = b2f(delta[(size_t)l * 512 + d]);
    const float xv = b2f(xcb[(size_t)l * 512 + d]);
    const float zs = b2f(zsb[(size_t)l * 512 + d]);
    const float du = dl * xv;
    const float4 B0 = *(const float4*)&Xs[lr][half * 8];
    const float4 B1 = *(const float4*)&Xs[lr][half * 8 + 4];
    const float4 C0 = *(const float4*)&Xs[lr][16 + half * 8];
    const float4 C1 = *(const float4*)&Xs[lr][16 + half * 8 + 4];
    const float Bv[8] = {B0.x, B0.y, B0.z, B0.w, B1.x, B1.y, B1.z, B1.w};
    const float Cv[8] = {C0.x, C0.y, C0.z, C0.w, C1.x, C1.y, C1.z, C1.w};
    float y = 0.f;
    #pragma unroll
    for (int n = 0; n < 8; ++n) {
      const float a = __expf(dl * Ad[n]);
      s[n] = fmaf(a, s[n], du * Bv[n]);
      y = fmaf(s[n], Cv[n], y);
    }
    y += __shfl_xor(y, 1);
    if (!half) yv[(size_t)l * 512 + d] = f2b((y + xv * Dd) * zs);
  }
}

extern "C" void kernel_launch(void* const* d_in, const int* in_sizes, int n_in,
                              void* d_out, int out_size, void* d_ws, size_t ws_size,
                              hipStream_t stream) {
  const float* x        = (const float*)d_in[0];
  const float* lin_w    = (const float*)d_in[1];
  const float* in_proj  = (const float*)d_in[2];
  const float* conv_w   = (const float*)d_in[3];
  const float* conv_b   = (const float*)d_in[4];
  const float* x_proj   = (const float*)d_in[5];
  const float* dt_w     = (const float*)d_in[6];
  const float* dt_b     = (const float*)d_in[7];
  const float* A_log    = (const float*)d_in[8];
  const float* D_param  = (const float*)d_in[9];
  const float* out_proj = (const float*)d_in[10];
  const float* gate_w   = (const float*)d_in[11];
  const float* gproj    = (const float*)d_in[12];
  const float* uproj    = (const float*)d_in[13];
  const float* dproj    = (const float*)d_in[14];
  const float* rms_a_w  = (const float*)d_in[15];
  const float* rms_f_w  = (const float*)d_in[16];
  const float* head_w1  = (const float*)d_in[17];
  const float* head_w2  = (const float*)d_in[18];

  char* p = (char*)d_ws;
  auto alloc = [&](size_t bytes) -> char* {
    char* r = p;
    p += (bytes + 255) & ~(size_t)255;
    return r;
  };

  // bf16 weight pool
  u16* lin_b  = (u16*)alloc(65536 * 2);
  u16* ipw_b  = (u16*)alloc((size_t)2097152 * 2);
  u16* xpw_b  = (u16*)alloc((size_t)196608 * 2);
  u16* opw_b  = (u16*)alloc((size_t)1048576 * 2);
  u16* gupw_b = (u16*)alloc((size_t)8388608 * 2);  // 16-wide gu interleave, expert-grouped
  u16* dpw_b  = (u16*)alloc((size_t)4194304 * 2);
  u16* hw1_b  = (u16*)alloc(65536 * 2);
  u16* hw2_b  = (u16*)alloc(8192 * 2);

  // activations
  u16* xT     = (u16*)alloc((size_t)kL * kDIM * 2);
  float* h    = (float*)alloc((size_t)kL * kDIM * 4);
  u16* hn     = (u16*)alloc((size_t)kL * kDIM * 2);
  u16* hb2    = (u16*)alloc((size_t)kL * kDIM * 2);
  float* xdbl = (float*)alloc((size_t)kL * 48 * 4);
  u16* fb     = (u16*)alloc((size_t)kL * kDIM * 2);
  u16* h2b    = (u16*)alloc((size_t)kL * kDIM * 2);
  u16* xz     = (u16*)alloc((size_t)kL * 1024 * 2);
  u16* xcb    = (u16*)alloc((size_t)kL * kDI * 2);
  u16* zsb    = (u16*)alloc((size_t)kL * kDI * 2);
  u16* yv     = (u16*)alloc((size_t)kL * kDI * 2);
  u16* delta  = (u16*)alloc((size_t)kL * kDI * 2);
  float* aprod = (float*)alloc((size_t)128 * 8192 * 4);
  float* bacc  = (float*)alloc((size_t)128 * 8192 * 4);
  float* sinit = (float*)alloc((size_t)128 * 8192 * 4);
  float* gp    = (float*)alloc((size_t)16 * 8192 * 4);
  float* gb    = (float*)alloc((size_t)16 * 8192 * 4);
  float* ginit = (float*)alloc((size_t)16 * 8192 * 4);
  float* hpart = (float*)alloc((size_t)2 * kL * kDIM * 4);

  if ((size_t)(p - (char*)d_ws) > ws_size) return;  // fail loudly

  // ---- weight conversion ----
  Cvt2 dd;
  int seg = 0, blk = 0;
  auto add = [&](const float* s, u16* d, int n, int mode) {
    dd.s[seg] = s; dd.d[seg] = d; dd.n[seg] = n; dd.mode[seg] = mode;
    dd.bstart[seg] = blk;
    blk += (n + 4095) / 4096;
    ++seg;
  };
  add(lin_w, lin_b, 65536, 0);
  add(in_proj, ipw_b, 2097152, 0);
  add(x_proj, xpw_b, 196608, 0);
  add(out_proj, opw_b, 1048576, 0);
  add(head_w1, hw1_b, 65536, 0);
  add(head_w2, hw2_b, 8192, 0);
  for (int i = 0; i < kNB; ++i) {
    add(gproj + (size_t)i * 524288, gupw_b + (size_t)i * 1048576, 524288, 1);
    add(uproj + (size_t)i * 524288, gupw_b + (size_t)i * 1048576 + 4096, 524288, 1);
  }
  add(dproj, dpw_b, 4194304, 2);
  dd.nseg = seg;
  dd.bstart[seg] = blk;
  cvt2_k<<<blk, 256, 0, stream>>>(dd);
  transpose_x_k<<<dim3(kL / 32, kDIM / 32), dim3(32, 8), 0, stream>>>(x, xT);

  // h = xT @ lin_w^T
  gemm_t<64, 128, 2, 4, 2, 0><<<dim3(128, 2, 1), 256, 0, stream>>>(
      xT, 256, lin_b, 256, h, 256, 256, 256, 0);
  rms_a_k<<<kL, 256, 0, stream>>>(h, rms_a_w, hn);

  for (int i = 0; i < kNB; ++i) {
    // in_proj: N=1024, K=256 -> xz bf16
    gemm_t<128, 128, 4, 4, 2, 2><<<dim3(64, 8, 1), 256, 0, stream>>>(
        hn, 256, ipw_b + (size_t)i * 262144, 256, xz, 1024, 1024, 256, 0);
    conv_silu_k<<<kL * kDI / 1024, 256, 0, stream>>>(xz, conv_w + (size_t)i * 2048,
                                                     conv_b + (size_t)i * 512, xcb, zsb, xdbl);
    // xdbl: N=48, K=512, split-K=8 atomic (xdbl zeroed by conv kernel)
    gemm_t<128, 48, 2, 3, 1, 4><<<dim3(64, 1, 8), 256, 0, stream>>>(
        xcb, 512, xpw_b + (size_t)i * 24576, 512, xdbl, 48, 48, 512, 0);
    scan_a_k<<<dim3(128, 4), 256, 0, stream>>>(xdbl, xcb, A_log + (size_t)i * 8192,
                                               dt_w + (size_t)i * 8192, dt_b + (size_t)i * 512,
                                               delta, aprod, bacc);
    scan_b1_k<<<512, 256, 0, stream>>>(aprod, bacc, gp, gb);
    scan_b2_k<<<32, 256, 0, stream>>>(gp, gb, ginit);
    scan_b3_k<<<512, 256, 0, stream>>>(aprod, bacc, ginit, sinit);
    scan_c_k<<<dim3(128, 4), 256, 0, stream>>>(xdbl, xcb, zsb, A_log + (size_t)i * 8192,
                                               delta, sinit, D_param + (size_t)i * 512, yv);
    // out_proj: split-K=2 -> 2 partial buffers (reduced in mega)
    gemm_t<128, 128, 4, 4, 2, 5><<<dim3(64, 2, 2), 256, 0, stream>>>(
        yv, 512, opw_b + (size_t)i * 131072, 512, hpart, 256, 256, 512, 2097152);
    // fused MoE (router + gu + GLU + dproj + rms_f + rms_a), LDS-staged weights
    moe_mega_k<<<256, 512, 0, stream>>>(h, hpart, gate_w + (size_t)i * 1024,
                                        gupw_b + (size_t)i * 1048576, dpw_b + (size_t)i * 524288,
                                        rms_f_w, rms_a_w, hb2, hn);
  }

  // head: lin -> silu(head1) -> head2 + sigmoid-transpose fused
  gemm_t<64, 128, 2, 4, 2, 2><<<dim3(128, 2, 1), 256, 0, stream>>>(
      hb2, 256, lin_b, 256, h2b, 256, 256, 256, 0);
  gemm_t<64, 128, 2, 4, 2, 3><<<dim3(128, 2, 1), 256, 0, stream>>>(
      h2b, 256, hw1_b, 256, fb, 256, 256, 256, 0);
  gemm_t<64, 128, 2, 4, 2, 7><<<dim3(128, 1, 1), 256, 0, stream>>>(
      fb, 256, hw2_b, 256, (float*)d_out, 32, 32, 256, 0);
}

// Round 8
// 1994.281 us; speedup vs baseline: 1.4218x; 1.0067x over previous
//
#include <hip/hip_runtime.h>

typedef unsigned short u16;
typedef unsigned int u32;
using bf16x8 = __attribute__((ext_vector_type(8))) short;
using f32x4 = __attribute__((ext_vector_type(4))) float;

constexpr int kL = 8192;
constexpr int kDIM = 256;
constexpr int kDI = 512;
constexpr int kNB = 8;
constexpr float kEPS = 1e-3f;

__device__ __forceinline__ u16 f2b(float f) {
  u32 x = __builtin_bit_cast(u32, f);
  x += 0x7fffu + ((x >> 16) & 1u);
  return (u16)(x >> 16);
}
__device__ __forceinline__ float b2f(u16 u) {
  return __builtin_bit_cast(float, (u32)u << 16);
}
__device__ __forceinline__ float sigm(float x) { return 1.f / (1.f + __expf(-x)); }
__device__ __forceinline__ float softplus_fast(float x) {
  return fmaxf(x, 0.f) + __logf(1.f + __expf(-fabsf(x)));
}

__device__ __forceinline__ void async_cp16(const void* g, void* l) {
  __builtin_amdgcn_global_load_lds((const __attribute__((address_space(1))) u32*)g,
                                   (__attribute__((address_space(3))) u32*)l, 16, 0, 0);
}

// ---------------- balanced vectorized weight conversion ----------------
// mode 0: identity.
// mode 1: gu 16-wide interleave with expert grouping:
//   src row (e*512 + j) -> dst row e*1024 + (j>>4)*32 + (j&15)  (u: dst ptr pre-offset +16 rows)
// mode 2: dproj permute (NB,NE,DIM,INNER) -> (NB, DIM, NE*INNER).
struct Cvt2 {
  const float* s[23];
  u16* d[23];
  int n[23];
  int mode[23];
  int bstart[24];
  int nseg;
};
__global__ __launch_bounds__(256) void cvt2_k(Cvt2 dd) {
  const int b = blockIdx.x;
  int seg = 0;
  for (int i = 1; i < dd.nseg; ++i) seg += (b >= dd.bstart[i]) ? 1 : 0;
  const int lb = b - dd.bstart[seg];
  const float* s = dd.s[seg];
  u16* d = dd.d[seg];
  const int n = dd.n[seg];
  const int mode = dd.mode[seg];
  #pragma unroll
  for (int it = 0; it < 4; ++it) {
    const int e4 = lb * 1024 + it * 256 + threadIdx.x;
    const int i = e4 * 4;
    if (i >= n) break;
    const float4 v = ((const float4*)s)[e4];
    ushort4 o = make_ushort4(f2b(v.x), f2b(v.y), f2b(v.z), f2b(v.w));
    size_t dst;
    if (mode == 0) {
      dst = (size_t)i;
    } else if (mode == 1) {
      const int row = i >> 8, col = i & 255;
      const int drow = (row >> 9) * 1024 + ((row >> 4) & 31) * 32 + (row & 15);
      dst = (size_t)drow * 256 + col;
    } else {
      const int bb = i >> 19, e = (i >> 17) & 3, nr = (i >> 9) & 255, j = i & 511;
      dst = (size_t)bb * 524288 + (size_t)nr * 2048 + e * 512 + j;
    }
    *(ushort4*)&d[dst] = o;
  }
}

// x (DIM, L) f32 -> xT (L, DIM) bf16
__global__ __launch_bounds__(256) void transpose_x_k(const float* __restrict__ x, u16* __restrict__ xT) {
  __shared__ float tile[32][33];
  int l0 = blockIdx.x * 32, d0 = blockIdx.y * 32;
  int tx = threadIdx.x, ty = threadIdx.y;
  #pragma unroll
  for (int i = 0; i < 32; i += 8)
    tile[ty + i][tx] = x[(size_t)(d0 + ty + i) * kL + l0 + tx];
  __syncthreads();
  #pragma unroll
  for (int i = 0; i < 32; i += 8)
    xT[(size_t)(l0 + ty + i) * kDIM + d0 + tx] = f2b(tile[tx][ty + i]);
}

// ---------------- templated MFMA GEMM: C(MxN) = A(MxK) @ W(NxK)^T ----------------
// MODE 0: f32 store; 2: bf16 store; 3: silu->bf16; 4: f32 atomicAdd (split-K);
// MODE 7: sigmoid + transposed store. Staging pointers hoisted out of the K-loop.
template <int BM, int BN, int TR, int TC, int WCN, int MODE>
__global__ __launch_bounds__(256) void gemm_t(
    const u16* __restrict__ A, int lda,
    const u16* __restrict__ W, int ldw,
    void* __restrict__ C, int ldc,
    int N, int K, int pstride)
{
  constexpr int BNR = (BN + 63) & ~63;
  constexpr int NA = BM * 64 / 2048;
  constexpr int NBt = BNR * 64 / 2048;
  __shared__ u16 As[BM * 64];
  __shared__ u16 Bs[BNR * 64];
  const int tid = threadIdx.x;
  const int lane = tid & 63;
  const int wave = tid >> 6;
  const int bm = blockIdx.x * BM;
  const int bn = blockIdx.y * BN;
  const int wrow = (wave / WCN) * (TR * 16);
  const int wcol = (wave % WCN) * (TC * 16);
  const int kchunk = K / (int)gridDim.z;
  const int kbeg = blockIdx.z * kchunk;
  const int niter = kchunk >> 6;

  const u16* aSrc[NA];
  int aDst[NA];
  #pragma unroll
  for (int it = 0; it < NA; ++it) {
    const int flat = (it * 256 + tid) * 8;
    const int r = flat >> 6;
    const int gc = ((((flat >> 3) & 7) ^ (r & 7)) << 3);
    aDst[it] = flat;
    aSrc[it] = A + (size_t)(bm + r) * lda + kbeg + gc;
  }
  const u16* bSrc[NBt];
  int bDst[NBt];
  #pragma unroll
  for (int it = 0; it < NBt; ++it) {
    const int flat = (it * 256 + tid) * 8;
    const int r = flat >> 6;
    const int gc = ((((flat >> 3) & 7) ^ (r & 7)) << 3);
    int n = bn + r;
    if (n > N - 1) n = N - 1;
    bDst[it] = flat;
    bSrc[it] = W + (size_t)n * ldw + kbeg + gc;
  }

  f32x4 acc[TR][TC];
  #pragma unroll
  for (int r = 0; r < TR; ++r)
    #pragma unroll
    for (int c = 0; c < TC; ++c)
      acc[r][c] = f32x4{0.f, 0.f, 0.f, 0.f};

  for (int ki = 0; ki < niter; ++ki) {
    #pragma unroll
    for (int it = 0; it < NA; ++it) {
      async_cp16(aSrc[it], &As[aDst[it]]);
      aSrc[it] += 64;
    }
    #pragma unroll
    for (int it = 0; it < NBt; ++it) {
      async_cp16(bSrc[it], &Bs[bDst[it]]);
      bSrc[it] += 64;
    }
    __syncthreads();
    #pragma unroll
    for (int kk = 0; kk < 64; kk += 32) {
      const int kc = (kk >> 3) + (lane >> 4);
      const int mrow = lane & 15;
      bf16x8 a[TR], b[TC];
      #pragma unroll
      for (int rr = 0; rr < TR; ++rr) {
        int row = wrow + rr * 16 + mrow;
        a[rr] = *(const bf16x8*)&As[row * 64 + ((kc ^ (row & 7)) << 3)];
      }
      #pragma unroll
      for (int cc = 0; cc < TC; ++cc) {
        int row = wcol + cc * 16 + mrow;
        b[cc] = *(const bf16x8*)&Bs[row * 64 + ((kc ^ (row & 7)) << 3)];
      }
      #pragma unroll
      for (int rr = 0; rr < TR; ++rr)
        #pragma unroll
        for (int cc = 0; cc < TC; ++cc)
          acc[rr][cc] = __builtin_amdgcn_mfma_f32_16x16x32_bf16(a[rr], b[cc], acc[rr][cc], 0, 0, 0);
    }
    __syncthreads();
  }

  const int colb = bn + wcol + (lane & 15);
  const int rowb = bm + wrow + ((lane >> 4) << 2);
  #pragma unroll
  for (int rr = 0; rr < TR; ++rr)
    #pragma unroll
    for (int cc = 0; cc < TC; ++cc) {
      int col = colb + cc * 16;
      if (col >= N) continue;
      #pragma unroll
      for (int i = 0; i < 4; ++i) {
        const int row = rowb + rr * 16 + i;
        size_t off = (size_t)row * ldc + col;
        float v = acc[rr][cc][i];
        if constexpr (MODE == 0) ((float*)C)[off] = v;
        else if constexpr (MODE == 2) ((u16*)C)[off] = f2b(v);
        else if constexpr (MODE == 3) ((u16*)C)[off] = f2b(v * sigm(v));
        else if constexpr (MODE == 4) atomicAdd(&((float*)C)[off], v);
        else if constexpr (MODE == 7) ((float*)C)[(size_t)col * kL + row] = sigm(v);
      }
    }
}

// ---------------- fused mega-kernel: out_proj + router + MoE + norms ----------------
// 256 blocks x 512 threads, 32 rows of h per block. LDS-staged weights (double-buffered).
// phase -2: stage yv rows -> Ts; hd = yv @ opw^T (K=512, dbuf Ws); Ts overlay -> hv = h + hd.
// phase -1: router top2 -> WeS; Ah = bf16(hv).
// phase 1 (per expert): gu GEMM from Ah + staged W; GLU mix -> Ts.
// phase 2 (per expert): macc += Ts @ dpw_e^T (K=512).
// epilogue: rms_f + residual + rms_a -> h, hb2, hn.
__global__ __launch_bounds__(512, 1) void moe_mega_k(
    float* __restrict__ h, const u16* __restrict__ yv, const u16* __restrict__ Wop,
    const float* __restrict__ gw,
    const u16* __restrict__ Wgu, const u16* __restrict__ Wd,
    const float* __restrict__ wf, const float* __restrict__ wa,
    u16* __restrict__ hb2, u16* __restrict__ hn)
{
  __shared__ u16 Ah[32 * 256];       // 16 KB, swizzled 16B chunks: chunk ^ (row&7)
  __shared__ u16 Ts[32 * 512];       // 32 KB, swizzled (f32 overlay between phases)
  __shared__ u16 Ws[2][256 * 64];    // 64 KB staging, swizzled
  __shared__ float WeS[32][4];
  const int tid = threadIdx.x;
  const int lane = tid & 63;
  const int quad = lane >> 4;
  const int m16 = lane & 15;
  const int wave = tid >> 6;         // 0..7
  const int wcol = wave * 32;
  const int r0 = blockIdx.x * 32;
  const int prow = tid >> 4;         // 0..31
  const int pcol = (tid & 15) * 16;

  auto stage_op = [&](int buf, int k0) {
    #pragma unroll
    for (int it = 0; it < 4; ++it) {
      const int flat = (it * 512 + tid) * 8;
      const int r = flat >> 6;
      const int gc = ((((flat >> 3) & 7) ^ (r & 7)) << 3);
      async_cp16(Wop + (size_t)r * 512 + k0 + gc, &Ws[buf][flat]);
    }
  };
  auto stage_gu = [&](int buf, int e, int nc, int k0) {
    #pragma unroll
    for (int it = 0; it < 4; ++it) {
      const int flat = (it * 512 + tid) * 8;
      const int r = flat >> 6;
      const int gc = ((((flat >> 3) & 7) ^ (r & 7)) << 3);
      async_cp16(Wgu + (size_t)(e * 1024 + nc * 256 + r) * 256 + k0 + gc, &Ws[buf][flat]);
    }
  };
  auto stage_dp = [&](int buf, int e, int k0) {
    #pragma unroll
    for (int it = 0; it < 4; ++it) {
      const int flat = (it * 512 + tid) * 8;
      const int r = flat >> 6;
      const int gc = ((((flat >> 3) & 7) ^ (r & 7)) << 3);
      async_cp16(Wd + (size_t)r * 2048 + e * 512 + k0 + gc, &Ws[buf][flat]);
    }
  };

  // ---- phase -2: stage yv -> Ts (swizzled), hd = yv @ opw^T ----
  #pragma unroll
  for (int it = 0; it < 4; ++it) {
    const int flat = (it * 512 + tid) * 8;
    const int row = flat >> 9;
    const int c = (flat >> 3) & 63;
    const int cs = (c & ~7) | ((c & 7) ^ (row & 7));
    async_cp16(yv + (size_t)(r0 + row) * 512 + cs * 8, &Ts[flat]);
  }
  f32x4 hacc[2][2];
  #pragma unroll
  for (int rt = 0; rt < 2; ++rt)
    #pragma unroll
    for (int ct = 0; ct < 2; ++ct) hacc[rt][ct] = f32x4{0.f, 0.f, 0.f, 0.f};
  stage_op(0, 0);
  __syncthreads();
  #pragma unroll
  for (int k0i = 0; k0i < 8; ++k0i) {
    if (k0i < 7) stage_op((k0i + 1) & 1, (k0i + 1) * 64);
    const u16* buf = Ws[k0i & 1];
    #pragma unroll
    for (int kk = 0; kk < 64; kk += 32) {
      const int kcs = (kk >> 3) + quad;
      bf16x8 a[2], b[2];
      #pragma unroll
      for (int rt = 0; rt < 2; ++rt) {
        const int row = rt * 16 + m16;
        const int ch = ((k0i * 64 + kk) >> 3) + quad;
        a[rt] = *(const bf16x8*)&Ts[row * 512 + ((ch ^ (row & 7)) << 3)];
      }
      #pragma unroll
      for (int ct = 0; ct < 2; ++ct) {
        const int n = wcol + ct * 16 + m16;
        b[ct] = *(const bf16x8*)&buf[n * 64 + ((kcs ^ (n & 7)) << 3)];
      }
      #pragma unroll
      for (int rt = 0; rt < 2; ++rt)
        #pragma unroll
        for (int ct = 0; ct < 2; ++ct)
          hacc[rt][ct] = __builtin_amdgcn_mfma_f32_16x16x32_bf16(a[rt], b[ct], hacc[rt][ct], 0, 0, 0);
    }
    __syncthreads();
  }
  // hd -> f32 overlay on Ts
  float* MoeS = (float*)Ts;
  #pragma unroll
  for (int rt = 0; rt < 2; ++rt)
    #pragma unroll
    for (int ct = 0; ct < 2; ++ct)
      #pragma unroll
      for (int i = 0; i < 4; ++i)
        MoeS[(rt * 16 + quad * 4 + i) * 256 + wcol + ct * 16 + m16] = hacc[rt][ct][i];
  __syncthreads();

  // ---- phase -1: hv = h + hd; router; Ah ----
  float hv[16];
  {
    const size_t base = (size_t)(r0 + prow) * 256 + pcol;
    #pragma unroll
    for (int j = 0; j < 16; j += 4) {
      const float4 v = *(const float4*)(h + base + j);
      hv[j] = v.x + MoeS[prow * 256 + pcol + j];
      hv[j + 1] = v.y + MoeS[prow * 256 + pcol + j + 1];
      hv[j + 2] = v.z + MoeS[prow * 256 + pcol + j + 2];
      hv[j + 3] = v.w + MoeS[prow * 256 + pcol + j + 3];
    }
  }
  {
    float p[4];
    #pragma unroll
    for (int e = 0; e < 4; ++e) {
      float s = 0.f;
      #pragma unroll
      for (int j = 0; j < 16; ++j) s += hv[j] * gw[e * 256 + pcol + j];
      p[e] = s;
    }
    #pragma unroll
    for (int o = 8; o > 0; o >>= 1) {
      p[0] += __shfl_xor(p[0], o); p[1] += __shfl_xor(p[1], o);
      p[2] += __shfl_xor(p[2], o); p[3] += __shfl_xor(p[3], o);
    }
    if ((tid & 15) == 0) {
      int i0 = 0;
      #pragma unroll
      for (int e = 1; e < 4; ++e) if (p[e] > p[i0]) i0 = e;
      int i1 = -1;
      #pragma unroll
      for (int e = 0; e < 4; ++e) {
        if (e == i0) continue;
        if (i1 < 0 || p[e] > p[i1]) i1 = e;
      }
      const float tt = __expf(p[i1] - p[i0]);
      float o0 = 1.f / (1.f + tt), o1 = tt / (1.f + tt);
      WeS[prow][0] = 0.f; WeS[prow][1] = 0.f; WeS[prow][2] = 0.f; WeS[prow][3] = 0.f;
      WeS[prow][i0] = o0; WeS[prow][i1] = o1;
    }
    #pragma unroll
    for (int cc = 0; cc < 2; ++cc) {
      const int chunk = (pcol >> 3) + cc;
      const int sw = ((chunk ^ (prow & 7)) << 3);
      u16 tmp[8];
      #pragma unroll
      for (int j = 0; j < 8; ++j) tmp[j] = f2b(hv[cc * 8 + j]);
      *(bf16x8*)&Ah[prow * 256 + sw] = *(bf16x8*)tmp;
    }
  }
  __syncthreads();

  f32x4 macc[2][2];
  #pragma unroll
  for (int rt = 0; rt < 2; ++rt)
    #pragma unroll
    for (int ct = 0; ct < 2; ++ct) macc[rt][ct] = f32x4{0.f, 0.f, 0.f, 0.f};

  for (int e = 0; e < 4; ++e) {
    // ---- phase 1 ----
    for (int nc = 0; nc < 4; ++nc) {
      f32x4 acc[2][2];
      #pragma unroll
      for (int rt = 0; rt < 2; ++rt)
        #pragma unroll
        for (int ct = 0; ct < 2; ++ct) acc[rt][ct] = f32x4{0.f, 0.f, 0.f, 0.f};
      stage_gu(0, e, nc, 0);
      __syncthreads();
      #pragma unroll
      for (int k0i = 0; k0i < 4; ++k0i) {
        if (k0i < 3) stage_gu((k0i + 1) & 1, e, nc, (k0i + 1) * 64);
        const u16* buf = Ws[k0i & 1];
        #pragma unroll
        for (int kk = 0; kk < 64; kk += 32) {
          const int kcs = (kk >> 3) + quad;
          bf16x8 a[2], b[2];
          #pragma unroll
          for (int rt = 0; rt < 2; ++rt) {
            const int row = rt * 16 + m16;
            const int ch = ((k0i * 64 + kk) >> 3) + quad;
            a[rt] = *(const bf16x8*)&Ah[row * 256 + ((ch ^ (row & 7)) << 3)];
          }
          #pragma unroll
          for (int ct = 0; ct < 2; ++ct) {
            const int n = wcol + ct * 16 + m16;
            b[ct] = *(const bf16x8*)&buf[n * 64 + ((kcs ^ (n & 7)) << 3)];
          }
          #pragma unroll
          for (int rt = 0; rt < 2; ++rt)
            #pragma unroll
            for (int ct = 0; ct < 2; ++ct)
              acc[rt][ct] = __builtin_amdgcn_mfma_f32_16x16x32_bf16(a[rt], b[ct], acc[rt][ct], 0, 0, 0);
        }
        __syncthreads();
      }
      // GLU mix -> Ts
      const int group = nc * 8 + wave;
      const int j = group * 16 + m16;
      #pragma unroll
      for (int rt = 0; rt < 2; ++rt)
        #pragma unroll
        for (int i = 0; i < 4; ++i) {
          const int row = rt * 16 + quad * 4 + i;
          const float g = acc[rt][0][i];
          const float u = acc[rt][1][i];
          const float val = g * sigm(g) * u * WeS[row][e];
          Ts[row * 512 + (((j >> 3) ^ (row & 7)) << 3) + (j & 7)] = f2b(val);
        }
    }
    __syncthreads();  // Ts complete
    // ---- phase 2 ----
    stage_dp(0, e, 0);
    __syncthreads();
    #pragma unroll
    for (int k0i = 0; k0i < 8; ++k0i) {
      if (k0i < 7) stage_dp((k0i + 1) & 1, e, (k0i + 1) * 64);
      const u16* buf = Ws[k0i & 1];
      #pragma unroll
      for (int kk = 0; kk < 64; kk += 32) {
        const int kcs = (kk >> 3) + quad;
        bf16x8 a[2], b[2];
        #pragma unroll
        for (int rt = 0; rt < 2; ++rt) {
          const int row = rt * 16 + m16;
          const int ch = ((k0i * 64 + kk) >> 3) + quad;
          a[rt] = *(const bf16x8*)&Ts[row * 512 + ((ch ^ (row & 7)) << 3)];
        }
        #pragma unroll
        for (int ct = 0; ct < 2; ++ct) {
          const int n = wcol + ct * 16 + m16;
          b[ct] = *(const bf16x8*)&buf[n * 64 + ((kcs ^ (n & 7)) << 3)];
        }
        #pragma unroll
        for (int rt = 0; rt < 2; ++rt)
          #pragma unroll
          for (int ct = 0; ct < 2; ++ct)
            macc[rt][ct] = __builtin_amdgcn_mfma_f32_16x16x32_bf16(a[rt], b[ct], macc[rt][ct], 0, 0, 0);
      }
      __syncthreads();
    }
  }

  // ---- epilogue ----
  #pragma unroll
  for (int rt = 0; rt < 2; ++rt)
    #pragma unroll
    for (int ct = 0; ct < 2; ++ct)
      #pragma unroll
      for (int i = 0; i < 4; ++i)
        MoeS[(rt * 16 + quad * 4 + i) * 256 + wcol + ct * 16 + m16] = macc[rt][ct][i];
  __syncthreads();

  float mv[16];
  float ss = 0.f;
  #pragma unroll
  for (int j = 0; j < 16; ++j) {
    mv[j] = MoeS[prow * 256 + pcol + j];
    ss += mv[j] * mv[j];
  }
  #pragma unroll
  for (int o = 8; o > 0; o >>= 1) ss += __shfl_xor(ss, o);
  const float r1 = rsqrtf(ss * (1.f / 256.f) + kEPS);
  float ss2 = 0.f;
  #pragma unroll
  for (int j = 0; j < 16; ++j) {
    hv[j] += wf[pcol + j] * mv[j] * r1;
    ss2 += hv[j] * hv[j];
  }
  #pragma unroll
  for (int o = 8; o > 0; o >>= 1) ss2 += __shfl_xor(ss2, o);
  const float r2 = rsqrtf(ss2 * (1.f / 256.f) + kEPS);

  const size_t base = (size_t)(r0 + prow) * 256 + pcol;
  #pragma unroll
  for (int j = 0; j < 16; j += 4)
    *(float4*)(h + base + j) = float4{hv[j], hv[j + 1], hv[j + 2], hv[j + 3]};
  #pragma unroll
  for (int j = 0; j < 16; j += 4) {
    *(ushort4*)(hb2 + base + j) = make_ushort4(f2b(hv[j]), f2b(hv[j + 1]), f2b(hv[j + 2]), f2b(hv[j + 3]));
    *(ushort4*)(hn + base + j) = make_ushort4(
        f2b(wa[pcol + j] * hv[j] * r2), f2b(wa[pcol + j + 1] * hv[j + 1] * r2),
        f2b(wa[pcol + j + 2] * hv[j + 2] * r2), f2b(wa[pcol + j + 3] * hv[j + 3] * r2));
  }
}

// ---------------- block-wide sum over 256 threads ----------------
__device__ __forceinline__ float block_sum256(float v) {
  #pragma unroll
  for (int o = 32; o > 0; o >>= 1) v += __shfl_down(v, o);
  __shared__ float red[4];
  __syncthreads();
  if ((threadIdx.x & 63) == 0) red[threadIdx.x >> 6] = v;
  __syncthreads();
  return red[0] + red[1] + red[2] + red[3];
}

__global__ __launch_bounds__(256) void rms_a_k(const float* __restrict__ h, const float* __restrict__ w,
                                               u16* __restrict__ hn) {
  const int l = blockIdx.x, t = threadIdx.x;
  const float v = h[(size_t)l * kDIM + t];
  const float ssum = block_sum256(v * v);
  const float r = rsqrtf(ssum * (1.f / 256.f) + kEPS);
  hn[(size_t)l * kDIM + t] = f2b(w[t] * v * r);
}

// causal depthwise conv (4 taps, 4 channels/thread) + bias + silu -> xcb; z*silu(z) -> zsb;
// also zeroes xdbl for the split-K atomic GEMM that follows.
__global__ __launch_bounds__(256) void conv_silu_k(const u16* __restrict__ xz, const float* __restrict__ cw,
                                                   const float* __restrict__ cb,
                                                   u16* __restrict__ xcb, u16* __restrict__ zsb,
                                                   float* __restrict__ xdbl) {
  const int i4 = blockIdx.x * 256 + threadIdx.x;  // L*DI/4
  if (i4 < 98304) *(float4*)&xdbl[i4 * 4] = float4{0.f, 0.f, 0.f, 0.f};
  const int l = i4 >> 7;
  const int d = (i4 & 127) * 4;
  float acc[4];
  const float4 cbv = *(const float4*)&cb[d];
  acc[0] = cbv.x; acc[1] = cbv.y; acc[2] = cbv.z; acc[3] = cbv.w;
  #pragma unroll
  for (int j = 0; j < 4; ++j) {
    const int ll = l - 3 + j;
    if (ll >= 0) {
      const ushort4 xv = *(const ushort4*)&xz[(size_t)ll * 1024 + d];
      acc[0] += cw[(d + 0) * 4 + j] * b2f(xv.x);
      acc[1] += cw[(d + 1) * 4 + j] * b2f(xv.y);
      acc[2] += cw[(d + 2) * 4 + j] * b2f(xv.z);
      acc[3] += cw[(d + 3) * 4 + j] * b2f(xv.w);
    }
  }
  ushort4 xo, zo;
  const ushort4 zv = *(const ushort4*)&xz[(size_t)l * 1024 + 512 + d];
  float z0 = b2f(zv.x), z1 = b2f(zv.y), z2 = b2f(zv.z), z3 = b2f(zv.w);
  xo.x = f2b(acc[0] * sigm(acc[0])); xo.y = f2b(acc[1] * sigm(acc[1]));
  xo.z = f2b(acc[2] * sigm(acc[2])); xo.w = f2b(acc[3] * sigm(acc[3]));
  zo.x = f2b(z0 * sigm(z0)); zo.y = f2b(z1 * sigm(z1));
  zo.z = f2b(z2 * sigm(z2)); zo.w = f2b(z3 * sigm(z3));
  *(ushort4*)&xcb[(size_t)l * 512 + d] = xo;
  *(ushort4*)&zsb[(size_t)l * 512 + d] = zo;
}

// ---------------- chunked selective scan; lane-pair state split ----------------
__global__ __launch_bounds__(256) void scan_a_k(const float* __restrict__ xdbl, const u16* __restrict__ xcb,
                                                const float* __restrict__ A_log, const float* __restrict__ dtw,
                                                const float* __restrict__ dtb,
                                                u16* __restrict__ delta,
                                                float* __restrict__ aprod, float* __restrict__ bacc) {
  const int c = blockIdx.x;
  const int t = threadIdx.x;
  const int half = t & 1;
  const int d = blockIdx.y * 128 + (t >> 1);
  const int l0 = c * 64;
  __shared__ float Xs[64][32];  // [lr][0:16)=dr, [16:32)=B
  for (int i = t; i < 2048; i += 256)
    Xs[i >> 5][i & 31] = xdbl[(size_t)(l0 + (i >> 5)) * 48 + (i & 31)];
  __syncthreads();
  float wd[8], Ad[8];
  #pragma unroll
  for (int j = 0; j < 8; ++j) wd[j] = dtw[d * 16 + half * 8 + j];
  const float bd = dtb[d];
  #pragma unroll
  for (int n = 0; n < 8; ++n) Ad[n] = -__expf(A_log[d * 16 + half * 8 + n]);
  float s[8], ap[8];
  #pragma unroll
  for (int n = 0; n < 8; ++n) { s[n] = 0.f; ap[n] = 1.f; }
  #pragma unroll 4
  for (int lr = 0; lr < 64; ++lr) {
    const float4 dr0 = *(const float4*)&Xs[lr][half * 8];
    const float4 dr1 = *(const float4*)&Xs[lr][half * 8 + 4];
    float p0 = dr0.x * wd[0] + dr0.y * wd[1] + dr0.z * wd[2] + dr0.w * wd[3];
    float p1 = dr1.x * wd[4] + dr1.y * wd[5] + dr1.z * wd[6] + dr1.w * wd[7];
    float dot = p0 + p1;
    dot += __shfl_xor(dot, 1);
    const float dl = softplus_fast(dot + bd);
    const int l = l0 + lr;
    if (!half) delta[(size_t)l * 512 + d] = f2b(dl);
    const float du = dl * b2f(xcb[(size_t)l * 512 + d]);
    const float4 B0 = *(const float4*)&Xs[lr][16 + half * 8];
    const float4 B1 = *(const float4*)&Xs[lr][16 + half * 8 + 4];
    const float Bv[8] = {B0.x, B0.y, B0.z, B0.w, B1.x, B1.y, B1.z, B1.w};
    #pragma unroll
    for (int n = 0; n < 8; ++n) {
      const float a = __expf(dl * Ad[n]);
      s[n] = fmaf(a, s[n], du * Bv[n]);
      ap[n] *= a;
    }
  }
  const int base = c * 8192 + d * 16 + half * 8;
  #pragma unroll
  for (int n = 0; n < 8; ++n) { aprod[base + n] = ap[n]; bacc[base + n] = s[n]; }
}

// chunk combine levels 1+2: 128 chunks = 16 groups x 8
__global__ __launch_bounds__(256) void scan_b1_k(const float* __restrict__ aprod, const float* __restrict__ bacc,
                                                 float* __restrict__ gp, float* __restrict__ gb) {
  const int idx = blockIdx.x * 256 + threadIdx.x;  // 8192*16
  const int st = idx & 8191, g = idx >> 13;
  float P = 1.f, S = 0.f;
  #pragma unroll
  for (int k = 0; k < 8; ++k) {
    const int c = g * 8 + k;
    const float a = aprod[(size_t)c * 8192 + st];
    S = fmaf(a, S, bacc[(size_t)c * 8192 + st]);
    P *= a;
  }
  gp[(size_t)g * 8192 + st] = P;
  gb[(size_t)g * 8192 + st] = S;
}

__global__ __launch_bounds__(256) void scan_b2_k(const float* __restrict__ gp, const float* __restrict__ gb,
                                                 float* __restrict__ ginit) {
  const int st = blockIdx.x * 256 + threadIdx.x;  // 8192
  float cur = 0.f;
  #pragma unroll
  for (int g = 0; g < 16; ++g) {
    ginit[(size_t)g * 8192 + st] = cur;
    cur = fmaf(gp[(size_t)g * 8192 + st], cur, gb[(size_t)g * 8192 + st]);
  }
}

// scan_c with inlined level-3 combine (reads ginit + folds <=7 chunk partials)
__global__ __launch_bounds__(256) void scan_c_k(const float* __restrict__ xdbl, const u16* __restrict__ xcb,
                                                const u16* __restrict__ zsb, const float* __restrict__ A_log,
                                                const u16* __restrict__ delta,
                                                const float* __restrict__ aprod, const float* __restrict__ bacc,
                                                const float* __restrict__ ginit,
                                                const float* __restrict__ Dp, u16* __restrict__ yv) {
  const int c = blockIdx.x;
  const int t = threadIdx.x;
  const int half = t & 1;
  const int d = blockIdx.y * 128 + (t >> 1);
  const int l0 = c * 64;
  __shared__ float Xs[64][32];  // [lr][0:16)=B, [16:32)=C
  for (int i = t; i < 2048; i += 256)
    Xs[i >> 5][i & 31] = xdbl[(size_t)(l0 + (i >> 5)) * 48 + 16 + (i & 31)];
  __syncthreads();
  float Ad[8];
  #pragma unroll
  for (int n = 0; n < 8; ++n) Ad[n] = -__expf(A_log[d * 16 + half * 8 + n]);
  float s[8];
  {
    const int g = c >> 3;
    const int stb = d * 16 + half * 8;
    const float4 g0 = *(const float4*)&ginit[(size_t)g * 8192 + stb];
    const float4 g1 = *(const float4*)&ginit[(size_t)g * 8192 + stb + 4];
    s[0] = g0.x; s[1] = g0.y; s[2] = g0.z; s[3] = g0.w;
    s[4] = g1.x; s[5] = g1.y; s[6] = g1.z; s[7] = g1.w;
    for (int cc = g * 8; cc < c; ++cc) {
      const float4 a0 = *(const float4*)&aprod[(size_t)cc * 8192 + stb];
      const float4 a1 = *(const float4*)&aprod[(size_t)cc * 8192 + stb + 4];
      const float4 b0 = *(const float4*)&bacc[(size_t)cc * 8192 + stb];
      const float4 b1 = *(const float4*)&bacc[(size_t)cc * 8192 + stb + 4];
      s[0] = fmaf(a0.x, s[0], b0.x); s[1] = fmaf(a0.y, s[1], b0.y);
      s[2] = fmaf(a0.z, s[2], b0.z); s[3] = fmaf(a0.w, s[3], b0.w);
      s[4] = fmaf(a1.x, s[4], b1.x); s[5] = fmaf(a1.y, s[5], b1.y);
      s[6] = fmaf(a1.z, s[6], b1.z); s[7] = fmaf(a1.w, s[7], b1.w);
    }
  }
  const float Dd = Dp[d];
  #pragma unroll 4
  for (int lr = 0; lr < 64; ++lr) {
    const int l = l0 + lr;
    const float dl = b2f(delta[(size_t)l * 512 + d]);
    const float xv = b2f(xcb[(size_t)l * 512 + d]);
    const float zs = b2f(zsb[(size_t)l * 512 + d]);
    const float du = dl * xv;
    const float4 B0 = *(const float4*)&Xs[lr][half * 8];
    const float4 B1 = *(const float4*)&Xs[lr][half * 8 + 4];
    const float4 C0 = *(const float4*)&Xs[lr][16 + half * 8];
    const float4 C1 = *(const float4*)&Xs[lr][16 + half * 8 + 4];
    const float Bv[8] = {B0.x, B0.y, B0.z, B0.w, B1.x, B1.y, B1.z, B1.w};
    const float Cv[8] = {C0.x, C0.y, C0.z, C0.w, C1.x, C1.y, C1.z, C1.w};
    float y = 0.f;
    #pragma unroll
    for (int n = 0; n < 8; ++n) {
      const float a = __expf(dl * Ad[n]);
      s[n] = fmaf(a, s[n], du * Bv[n]);
      y = fmaf(s[n], Cv[n], y);
    }
    y += __shfl_xor(y, 1);
    if (!half) yv[(size_t)l * 512 + d] = f2b((y + xv * Dd) * zs);
  }
}

extern "C" void kernel_launch(void* const* d_in, const int* in_sizes, int n_in,
                              void* d_out, int out_size, void* d_ws, size_t ws_size,
                              hipStream_t stream) {
  const float* x        = (const float*)d_in[0];
  const float* lin_w    = (const float*)d_in[1];
  const float* in_proj  = (const float*)d_in[2];
  const float* conv_w   = (const float*)d_in[3];
  const float* conv_b   = (const float*)d_in[4];
  const float* x_proj   = (const float*)d_in[5];
  const float* dt_w     = (const float*)d_in[6];
  const float* dt_b     = (const float*)d_in[7];
  const float* A_log    = (const float*)d_in[8];
  const float* D_param  = (const float*)d_in[9];
  const float* out_proj = (const float*)d_in[10];
  const float* gate_w   = (const float*)d_in[11];
  const float* gproj    = (const float*)d_in[12];
  const float* uproj    = (const float*)d_in[13];
  const float* dproj    = (const float*)d_in[14];
  const float* rms_a_w  = (const float*)d_in[15];
  const float* rms_f_w  = (const float*)d_in[16];
  const float* head_w1  = (const float*)d_in[17];
  const float* head_w2  = (const float*)d_in[18];

  char* p = (char*)d_ws;
  auto alloc = [&](size_t bytes) -> char* {
    char* r = p;
    p += (bytes + 255) & ~(size_t)255;
    return r;
  };

  // bf16 weight pool
  u16* lin_b  = (u16*)alloc(65536 * 2);
  u16* ipw_b  = (u16*)alloc((size_t)2097152 * 2);
  u16* xpw_b  = (u16*)alloc((size_t)196608 * 2);
  u16* opw_b  = (u16*)alloc((size_t)1048576 * 2);
  u16* gupw_b = (u16*)alloc((size_t)8388608 * 2);  // 16-wide gu interleave, expert-grouped
  u16* dpw_b  = (u16*)alloc((size_t)4194304 * 2);
  u16* hw1_b  = (u16*)alloc(65536 * 2);
  u16* hw2_b  = (u16*)alloc(8192 * 2);

  // activations
  u16* xT     = (u16*)alloc((size_t)kL * kDIM * 2);
  float* h    = (float*)alloc((size_t)kL * kDIM * 4);
  u16* hn     = (u16*)alloc((size_t)kL * kDIM * 2);
  u16* hb2    = (u16*)alloc((size_t)kL * kDIM * 2);
  float* xdbl = (float*)alloc((size_t)kL * 48 * 4);
  u16* fb     = (u16*)alloc((size_t)kL * kDIM * 2);
  u16* h2b    = (u16*)alloc((size_t)kL * kDIM * 2);
  u16* xz     = (u16*)alloc((size_t)kL * 1024 * 2);
  u16* xcb    = (u16*)alloc((size_t)kL * kDI * 2);
  u16* zsb    = (u16*)alloc((size_t)kL * kDI * 2);
  u16* yv     = (u16*)alloc((size_t)kL * kDI * 2);
  u16* delta  = (u16*)alloc((size_t)kL * kDI * 2);
  float* aprod = (float*)alloc((size_t)128 * 8192 * 4);
  float* bacc  = (float*)alloc((size_t)128 * 8192 * 4);
  float* gp    = (float*)alloc((size_t)16 * 8192 * 4);
  float* gb    = (float*)alloc((size_t)16 * 8192 * 4);
  float* ginit = (float*)alloc((size_t)16 * 8192 * 4);

  if ((size_t)(p - (char*)d_ws) > ws_size) return;  // fail loudly

  // ---- weight conversion ----
  Cvt2 dd;
  int seg = 0, blk = 0;
  auto add = [&](const float* s, u16* d, int n, int mode) {
    dd.s[seg] = s; dd.d[seg] = d; dd.n[seg] = n; dd.mode[seg] = mode;
    dd.bstart[seg] = blk;
    blk += (n + 4095) / 4096;
    ++seg;
  };
  add(lin_w, lin_b, 65536, 0);
  add(in_proj, ipw_b, 2097152, 0);
  add(x_proj, xpw_b, 196608, 0);
  add(out_proj, opw_b, 1048576, 0);
  add(head_w1, hw1_b, 65536, 0);
  add(head_w2, hw2_b, 8192, 0);
  for (int i = 0; i < kNB; ++i) {
    add(gproj + (size_t)i * 524288, gupw_b + (size_t)i * 1048576, 524288, 1);
    add(uproj + (size_t)i * 524288, gupw_b + (size_t)i * 1048576 + 4096, 524288, 1);
  }
  add(dproj, dpw_b, 4194304, 2);
  dd.nseg = seg;
  dd.bstart[seg] = blk;
  cvt2_k<<<blk, 256, 0, stream>>>(dd);
  transpose_x_k<<<dim3(kL / 32, kDIM / 32), dim3(32, 8), 0, stream>>>(x, xT);

  // h = xT @ lin_w^T
  gemm_t<64, 128, 2, 4, 2, 0><<<dim3(128, 2, 1), 256, 0, stream>>>(
      xT, 256, lin_b, 256, h, 256, 256, 256, 0);
  rms_a_k<<<kL, 256, 0, stream>>>(h, rms_a_w, hn);

  for (int i = 0; i < kNB; ++i) {
    // in_proj: N=1024, K=256 -> xz bf16
    gemm_t<128, 128, 4, 4, 2, 2><<<dim3(64, 8, 1), 256, 0, stream>>>(
        hn, 256, ipw_b + (size_t)i * 262144, 256, xz, 1024, 1024, 256, 0);
    conv_silu_k<<<kL * kDI / 1024, 256, 0, stream>>>(xz, conv_w + (size_t)i * 2048,
                                                     conv_b + (size_t)i * 512, xcb, zsb, xdbl);
    // xdbl: N=48, K=512, split-K=8 atomic (xdbl zeroed by conv kernel)
    gemm_t<128, 48, 2, 3, 1, 4><<<dim3(64, 1, 8), 256, 0, stream>>>(
        xcb, 512, xpw_b + (size_t)i * 24576, 512, xdbl, 48, 48, 512, 0);
    scan_a_k<<<dim3(128, 4), 256, 0, stream>>>(xdbl, xcb, A_log + (size_t)i * 8192,
                                               dt_w + (size_t)i * 8192, dt_b + (size_t)i * 512,
                                               delta, aprod, bacc);
    scan_b1_k<<<512, 256, 0, stream>>>(aprod, bacc, gp, gb);
    scan_b2_k<<<32, 256, 0, stream>>>(gp, gb, ginit);
    scan_c_k<<<dim3(128, 4), 256, 0, stream>>>(xdbl, xcb, zsb, A_log + (size_t)i * 8192,
                                               delta, aprod, bacc, ginit,
                                               D_param + (size_t)i * 512, yv);
    // fused mega: out_proj + router + gu + GLU + dproj + rms_f + rms_a
    moe_mega_k<<<256, 512, 0, stream>>>(h, yv, opw_b + (size_t)i * 131072,
                                        gate_w + (size_t)i * 1024,
                                        gupw_b + (size_t)i * 1048576, dpw_b + (size_t)i * 524288,
                                        rms_f_w, rms_a_w, hb2, hn);
  }

  // head: lin -> silu(head1) -> head2 + sigmoid-transpose fused
  gemm_t<64, 128, 2, 4, 2, 2><<<dim3(128, 2, 1), 256, 0, stream>>>(
      hb2, 256, lin_b, 256, h2b, 256, 256, 256, 0);
  gemm_t<64, 128, 2, 4, 2, 3><<<dim3(128, 2, 1), 256, 0, stream>>>(
      h2b, 256, hw1_b, 256, fb, 256, 256, 256, 0);
  gemm_t<64, 128, 2, 4, 2, 7><<<dim3(128, 1, 1), 256, 0, stream>>>(
      fb, 256, hw2_b, 256, (float*)d_out, 32, 32, 256, 0);
}

// Round 9
// 1753.335 us; speedup vs baseline: 1.6172x; 1.1374x over previous
//
#include <hip/hip_runtime.h>

typedef unsigned short u16;
typedef unsigned int u32;
using bf16x8 = __attribute__((ext_vector_type(8))) short;
using f32x4 = __attribute__((ext_vector_type(4))) float;

constexpr int kL = 8192;
constexpr int kDIM = 256;
constexpr int kDI = 512;
constexpr int kNB = 8;
constexpr float kEPS = 1e-3f;

__device__ __forceinline__ u16 f2b(float f) {
  u32 x = __builtin_bit_cast(u32, f);
  x += 0x7fffu + ((x >> 16) & 1u);
  return (u16)(x >> 16);
}
__device__ __forceinline__ float b2f(u16 u) {
  return __builtin_bit_cast(float, (u32)u << 16);
}
__device__ __forceinline__ float sigm(float x) { return 1.f / (1.f + __expf(-x)); }
__device__ __forceinline__ float softplus_fast(float x) {
  return fmaxf(x, 0.f) + __logf(1.f + __expf(-fabsf(x)));
}

__device__ __forceinline__ void async_cp16(const void* g, void* l) {
  __builtin_amdgcn_global_load_lds((const __attribute__((address_space(1))) u32*)g,
                                   (__attribute__((address_space(3))) u32*)l, 16, 0, 0);
}

// per-wave waitcnt: gfx9 simm16 = vmcnt[3:0] | expcnt<<4 | lgkmcnt<<8 | vmcnt_hi<<14
#define WAIT_VM4() __builtin_amdgcn_s_waitcnt(0x0F74)
#define WAIT_VM0() __builtin_amdgcn_s_waitcnt(0x0F70)
#define WBAR() __builtin_amdgcn_wave_barrier()

// ---------------- balanced vectorized weight conversion ----------------
// mode 0: identity.
// mode 1: gu 16-wide interleave with expert grouping:
//   src row (e*512 + j) -> dst row e*1024 + (j>>4)*32 + (j&15)  (u: dst ptr pre-offset +16 rows)
// mode 2: dproj permute (NB,NE,DIM,INNER) -> (NB, DIM, NE*INNER).
struct Cvt2 {
  const float* s[23];
  u16* d[23];
  int n[23];
  int mode[23];
  int bstart[24];
  int nseg;
};
__global__ __launch_bounds__(256) void cvt2_k(Cvt2 dd) {
  const int b = blockIdx.x;
  int seg = 0;
  for (int i = 1; i < dd.nseg; ++i) seg += (b >= dd.bstart[i]) ? 1 : 0;
  const int lb = b - dd.bstart[seg];
  const float* s = dd.s[seg];
  u16* d = dd.d[seg];
  const int n = dd.n[seg];
  const int mode = dd.mode[seg];
  #pragma unroll
  for (int it = 0; it < 4; ++it) {
    const int e4 = lb * 1024 + it * 256 + threadIdx.x;
    const int i = e4 * 4;
    if (i >= n) break;
    const float4 v = ((const float4*)s)[e4];
    ushort4 o = make_ushort4(f2b(v.x), f2b(v.y), f2b(v.z), f2b(v.w));
    size_t dst;
    if (mode == 0) {
      dst = (size_t)i;
    } else if (mode == 1) {
      const int row = i >> 8, col = i & 255;
      const int drow = (row >> 9) * 1024 + ((row >> 4) & 31) * 32 + (row & 15);
      dst = (size_t)drow * 256 + col;
    } else {
      const int bb = i >> 19, e = (i >> 17) & 3, nr = (i >> 9) & 255, j = i & 511;
      dst = (size_t)bb * 524288 + (size_t)nr * 2048 + e * 512 + j;
    }
    *(ushort4*)&d[dst] = o;
  }
}

// x (DIM, L) f32 -> xT (L, DIM) bf16
__global__ __launch_bounds__(256) void transpose_x_k(const float* __restrict__ x, u16* __restrict__ xT) {
  __shared__ float tile[32][33];
  int l0 = blockIdx.x * 32, d0 = blockIdx.y * 32;
  int tx = threadIdx.x, ty = threadIdx.y;
  #pragma unroll
  for (int i = 0; i < 32; i += 8)
    tile[ty + i][tx] = x[(size_t)(d0 + ty + i) * kL + l0 + tx];
  __syncthreads();
  #pragma unroll
  for (int i = 0; i < 32; i += 8)
    xT[(size_t)(l0 + ty + i) * kDIM + d0 + tx] = f2b(tile[tx][ty + i]);
}

// ---------------- templated MFMA GEMM: C(MxN) = A(MxK) @ W(NxK)^T ----------------
// MODE 0: f32 store; 2: bf16 store; 3: silu->bf16; 4: f32 atomicAdd (split-K);
// MODE 7: sigmoid + transposed store. Staging pointers hoisted out of the K-loop.
template <int BM, int BN, int TR, int TC, int WCN, int MODE>
__global__ __launch_bounds__(256) void gemm_t(
    const u16* __restrict__ A, int lda,
    const u16* __restrict__ W, int ldw,
    void* __restrict__ C, int ldc,
    int N, int K, int pstride)
{
  constexpr int BNR = (BN + 63) & ~63;
  constexpr int NA = BM * 64 / 2048;
  constexpr int NBt = BNR * 64 / 2048;
  __shared__ u16 As[BM * 64];
  __shared__ u16 Bs[BNR * 64];
  const int tid = threadIdx.x;
  const int lane = tid & 63;
  const int wave = tid >> 6;
  const int bm = blockIdx.x * BM;
  const int bn = blockIdx.y * BN;
  const int wrow = (wave / WCN) * (TR * 16);
  const int wcol = (wave % WCN) * (TC * 16);
  const int kchunk = K / (int)gridDim.z;
  const int kbeg = blockIdx.z * kchunk;
  const int niter = kchunk >> 6;

  const u16* aSrc[NA];
  int aDst[NA];
  #pragma unroll
  for (int it = 0; it < NA; ++it) {
    const int flat = (it * 256 + tid) * 8;
    const int r = flat >> 6;
    const int gc = ((((flat >> 3) & 7) ^ (r & 7)) << 3);
    aDst[it] = flat;
    aSrc[it] = A + (size_t)(bm + r) * lda + kbeg + gc;
  }
  const u16* bSrc[NBt];
  int bDst[NBt];
  #pragma unroll
  for (int it = 0; it < NBt; ++it) {
    const int flat = (it * 256 + tid) * 8;
    const int r = flat >> 6;
    const int gc = ((((flat >> 3) & 7) ^ (r & 7)) << 3);
    int n = bn + r;
    if (n > N - 1) n = N - 1;
    bDst[it] = flat;
    bSrc[it] = W + (size_t)n * ldw + kbeg + gc;
  }

  f32x4 acc[TR][TC];
  #pragma unroll
  for (int r = 0; r < TR; ++r)
    #pragma unroll
    for (int c = 0; c < TC; ++c)
      acc[r][c] = f32x4{0.f, 0.f, 0.f, 0.f};

  for (int ki = 0; ki < niter; ++ki) {
    #pragma unroll
    for (int it = 0; it < NA; ++it) {
      async_cp16(aSrc[it], &As[aDst[it]]);
      aSrc[it] += 64;
    }
    #pragma unroll
    for (int it = 0; it < NBt; ++it) {
      async_cp16(bSrc[it], &Bs[bDst[it]]);
      bSrc[it] += 64;
    }
    __syncthreads();
    #pragma unroll
    for (int kk = 0; kk < 64; kk += 32) {
      const int kc = (kk >> 3) + (lane >> 4);
      const int mrow = lane & 15;
      bf16x8 a[TR], b[TC];
      #pragma unroll
      for (int rr = 0; rr < TR; ++rr) {
        int row = wrow + rr * 16 + mrow;
        a[rr] = *(const bf16x8*)&As[row * 64 + ((kc ^ (row & 7)) << 3)];
      }
      #pragma unroll
      for (int cc = 0; cc < TC; ++cc) {
        int row = wcol + cc * 16 + mrow;
        b[cc] = *(const bf16x8*)&Bs[row * 64 + ((kc ^ (row & 7)) << 3)];
      }
      #pragma unroll
      for (int rr = 0; rr < TR; ++rr)
        #pragma unroll
        for (int cc = 0; cc < TC; ++cc)
          acc[rr][cc] = __builtin_amdgcn_mfma_f32_16x16x32_bf16(a[rr], b[cc], acc[rr][cc], 0, 0, 0);
    }
    __syncthreads();
  }

  const int colb = bn + wcol + (lane & 15);
  const int rowb = bm + wrow + ((lane >> 4) << 2);
  #pragma unroll
  for (int rr = 0; rr < TR; ++rr)
    #pragma unroll
    for (int cc = 0; cc < TC; ++cc) {
      int col = colb + cc * 16;
      if (col >= N) continue;
      #pragma unroll
      for (int i = 0; i < 4; ++i) {
        const int row = rowb + rr * 16 + i;
        size_t off = (size_t)row * ldc + col;
        float v = acc[rr][cc][i];
        if constexpr (MODE == 0) ((float*)C)[off] = v;
        else if constexpr (MODE == 2) ((u16*)C)[off] = f2b(v);
        else if constexpr (MODE == 3) ((u16*)C)[off] = f2b(v * sigm(v));
        else if constexpr (MODE == 4) atomicAdd(&((float*)C)[off], v);
        else if constexpr (MODE == 7) ((float*)C)[(size_t)col * kL + row] = sigm(v);
      }
    }
}

// ---------------- fused mega-kernel: out_proj + router + MoE + norms ----------------
// 256 blocks x 512 threads, 32 rows of h per block.
// W staging is PER-WAVE private (each wave consumes only its own 32 W-rows), double-buffered,
// synchronized with per-wave s_waitcnt vmcnt(N) — NO block barriers inside k-loops.
// Block barriers only at Ts/Ah produce-consume handoffs (~13 total).
__global__ __launch_bounds__(512, 1) void moe_mega_k(
    float* __restrict__ h, const u16* __restrict__ yv, const u16* __restrict__ Wop,
    const float* __restrict__ gw,
    const u16* __restrict__ Wgu, const u16* __restrict__ Wd,
    const float* __restrict__ wf, const float* __restrict__ wa,
    u16* __restrict__ hb2, u16* __restrict__ hn)
{
  __shared__ u16 Ah[32 * 256];       // 16 KB, swizzled 16B chunks: chunk ^ (row&7)
  __shared__ u16 Ts[32 * 512];       // 32 KB, swizzled (f32 overlay between phases)
  __shared__ u16 Ws[2][256 * 64];    // 2 x 32 KB; wave w owns [w*2048, (w+1)*2048) of each
  __shared__ float WeS[32][4];
  const int tid = threadIdx.x;
  const int lane = tid & 63;
  const int quad = lane >> 4;
  const int m16 = lane & 15;
  const int wave = tid >> 6;         // 0..7
  const int wcol = wave * 32;
  const int r0 = blockIdx.x * 32;
  const int prow = tid >> 4;         // 0..31
  const int pcol = (tid & 15) * 16;

  u16* const myW0 = &Ws[0][wave * 2048];
  u16* const myW1 = &Ws[1][wave * 2048];

  // per-wave stage: rows [0,32) of src (stride elements), cols [k0, k0+64), swizzled
  auto stage_rows = [&](u16* dst, const u16* src, int stride, int k0) {
    #pragma unroll
    for (int it = 0; it < 4; ++it) {
      const int flat = (it * 64 + lane) * 8;
      const int r = flat >> 6;
      const int gc = ((((flat >> 3) & 7) ^ (r & 7)) << 3);
      async_cp16(src + (size_t)r * stride + k0 + gc, dst + flat);
    }
  };

  // ---- phase -2: stage yv -> Ts (block-shared); hd = yv @ opw^T with per-wave W ----
  #pragma unroll
  for (int it = 0; it < 4; ++it) {
    const int flat = (it * 512 + tid) * 8;
    const int row = flat >> 9;
    const int c = (flat >> 3) & 63;
    const int cs = (c & ~7) | ((c & 7) ^ (row & 7));
    async_cp16(yv + (size_t)(r0 + row) * 512 + cs * 8, &Ts[flat]);
  }
  const u16* opsrc = Wop + (size_t)wcol * 512;
  stage_rows(myW0, opsrc, 512, 0);
  __syncthreads();  // drains vmcnt(0): yv visible block-wide, myW0 ready

  f32x4 hacc[2][2];
  #pragma unroll
  for (int rt = 0; rt < 2; ++rt)
    #pragma unroll
    for (int ct = 0; ct < 2; ++ct) hacc[rt][ct] = f32x4{0.f, 0.f, 0.f, 0.f};
  {
    int pb = 0;
    #pragma unroll
    for (int k0i = 0; k0i < 8; ++k0i) {
      if (k0i < 7) {
        stage_rows(pb ? myW0 : myW1, opsrc, 512, (k0i + 1) * 64);
        WAIT_VM4();
      } else {
        WAIT_VM0();
      }
      WBAR();
      const u16* buf = pb ? myW1 : myW0;
      #pragma unroll
      for (int kk = 0; kk < 64; kk += 32) {
        const int kcs = (kk >> 3) + quad;
        bf16x8 a[2], b[2];
        #pragma unroll
        for (int rt = 0; rt < 2; ++rt) {
          const int row = rt * 16 + m16;
          const int ch = ((k0i * 64 + kk) >> 3) + quad;
          a[rt] = *(const bf16x8*)&Ts[row * 512 + ((ch ^ (row & 7)) << 3)];
        }
        #pragma unroll
        for (int ct = 0; ct < 2; ++ct) {
          const int rl = ct * 16 + m16;
          b[ct] = *(const bf16x8*)&buf[rl * 64 + ((kcs ^ (rl & 7)) << 3)];
        }
        #pragma unroll
        for (int rt = 0; rt < 2; ++rt)
          #pragma unroll
          for (int ct = 0; ct < 2; ++ct)
            hacc[rt][ct] = __builtin_amdgcn_mfma_f32_16x16x32_bf16(a[rt], b[ct], hacc[rt][ct], 0, 0, 0);
      }
      WBAR();
      pb ^= 1;
    }
  }
  __syncthreads();  // all waves done reading Ts (yv tile) before overlay write

  // hd -> f32 overlay on Ts
  float* MoeS = (float*)Ts;
  #pragma unroll
  for (int rt = 0; rt < 2; ++rt)
    #pragma unroll
    for (int ct = 0; ct < 2; ++ct)
      #pragma unroll
      for (int i = 0; i < 4; ++i)
        MoeS[(rt * 16 + quad * 4 + i) * 256 + wcol + ct * 16 + m16] = hacc[rt][ct][i];
  __syncthreads();

  // ---- phase -1: hv = h + hd; router; Ah ----
  float hv[16];
  {
    const size_t base = (size_t)(r0 + prow) * 256 + pcol;
    #pragma unroll
    for (int j = 0; j < 16; j += 4) {
      const float4 v = *(const float4*)(h + base + j);
      hv[j] = v.x + MoeS[prow * 256 + pcol + j];
      hv[j + 1] = v.y + MoeS[prow * 256 + pcol + j + 1];
      hv[j + 2] = v.z + MoeS[prow * 256 + pcol + j + 2];
      hv[j + 3] = v.w + MoeS[prow * 256 + pcol + j + 3];
    }
  }
  {
    float p[4];
    #pragma unroll
    for (int e = 0; e < 4; ++e) {
      float s = 0.f;
      #pragma unroll
      for (int j = 0; j < 16; ++j) s += hv[j] * gw[e * 256 + pcol + j];
      p[e] = s;
    }
    #pragma unroll
    for (int o = 8; o > 0; o >>= 1) {
      p[0] += __shfl_xor(p[0], o); p[1] += __shfl_xor(p[1], o);
      p[2] += __shfl_xor(p[2], o); p[3] += __shfl_xor(p[3], o);
    }
    if ((tid & 15) == 0) {
      int i0 = 0;
      #pragma unroll
      for (int e = 1; e < 4; ++e) if (p[e] > p[i0]) i0 = e;
      int i1 = -1;
      #pragma unroll
      for (int e = 0; e < 4; ++e) {
        if (e == i0) continue;
        if (i1 < 0 || p[e] > p[i1]) i1 = e;
      }
      const float tt = __expf(p[i1] - p[i0]);
      float o0 = 1.f / (1.f + tt), o1 = tt / (1.f + tt);
      WeS[prow][0] = 0.f; WeS[prow][1] = 0.f; WeS[prow][2] = 0.f; WeS[prow][3] = 0.f;
      WeS[prow][i0] = o0; WeS[prow][i1] = o1;
    }
    #pragma unroll
    for (int cc = 0; cc < 2; ++cc) {
      const int chunk = (pcol >> 3) + cc;
      const int sw = ((chunk ^ (prow & 7)) << 3);
      u16 tmp[8];
      #pragma unroll
      for (int j = 0; j < 8; ++j) tmp[j] = f2b(hv[cc * 8 + j]);
      *(bf16x8*)&Ah[prow * 256 + sw] = *(bf16x8*)tmp;
    }
  }
  __syncthreads();

  f32x4 macc[2][2];
  #pragma unroll
  for (int rt = 0; rt < 2; ++rt)
    #pragma unroll
    for (int ct = 0; ct < 2; ++ct) macc[rt][ct] = f32x4{0.f, 0.f, 0.f, 0.f};

  for (int e = 0; e < 4; ++e) {
    // ---- phase 1: per-wave staged gu, barrier-free k-loops ----
    #pragma unroll
    for (int nc = 0; nc < 4; ++nc) {
      f32x4 acc[2][2];
      #pragma unroll
      for (int rt = 0; rt < 2; ++rt)
        #pragma unroll
        for (int ct = 0; ct < 2; ++ct) acc[rt][ct] = f32x4{0.f, 0.f, 0.f, 0.f};
      const u16* gusrc = Wgu + (size_t)(e * 1024 + nc * 256 + wcol) * 256;
      stage_rows(myW0, gusrc, 256, 0);
      int pb = 0;
      #pragma unroll
      for (int k0i = 0; k0i < 4; ++k0i) {
        if (k0i < 3) {
          stage_rows(pb ? myW0 : myW1, gusrc, 256, (k0i + 1) * 64);
          WAIT_VM4();
        } else {
          WAIT_VM0();
        }
        WBAR();
        const u16* buf = pb ? myW1 : myW0;
        #pragma unroll
        for (int kk = 0; kk < 64; kk += 32) {
          const int kcs = (kk >> 3) + quad;
          bf16x8 a[2], b[2];
          #pragma unroll
          for (int rt = 0; rt < 2; ++rt) {
            const int row = rt * 16 + m16;
            const int ch = ((k0i * 64 + kk) >> 3) + quad;
            a[rt] = *(const bf16x8*)&Ah[row * 256 + ((ch ^ (row & 7)) << 3)];
          }
          #pragma unroll
          for (int ct = 0; ct < 2; ++ct) {
            const int rl = ct * 16 + m16;
            b[ct] = *(const bf16x8*)&buf[rl * 64 + ((kcs ^ (rl & 7)) << 3)];
          }
          #pragma unroll
          for (int rt = 0; rt < 2; ++rt)
            #pragma unroll
            for (int ct = 0; ct < 2; ++ct)
              acc[rt][ct] = __builtin_amdgcn_mfma_f32_16x16x32_bf16(a[rt], b[ct], acc[rt][ct], 0, 0, 0);
        }
        WBAR();
        pb ^= 1;
      }
      // GLU mix -> Ts
      const int group = nc * 8 + wave;
      const int j = group * 16 + m16;
      #pragma unroll
      for (int rt = 0; rt < 2; ++rt)
        #pragma unroll
        for (int i = 0; i < 4; ++i) {
          const int row = rt * 16 + quad * 4 + i;
          const float g = acc[rt][0][i];
          const float u = acc[rt][1][i];
          const float val = g * sigm(g) * u * WeS[row][e];
          Ts[row * 512 + (((j >> 3) ^ (row & 7)) << 3) + (j & 7)] = f2b(val);
        }
    }
    __syncthreads();  // Ts complete (all waves)
    // ---- phase 2: per-wave staged dproj, barrier-free k-loop ----
    {
      const u16* dpsrc = Wd + (size_t)wcol * 2048 + e * 512;
      stage_rows(myW0, dpsrc, 2048, 0);
      int pb = 0;
      #pragma unroll
      for (int k0i = 0; k0i < 8; ++k0i) {
        if (k0i < 7) {
          stage_rows(pb ? myW0 : myW1, dpsrc, 2048, (k0i + 1) * 64);
          WAIT_VM4();
        } else {
          WAIT_VM0();
        }
        WBAR();
        const u16* buf = pb ? myW1 : myW0;
        #pragma unroll
        for (int kk = 0; kk < 64; kk += 32) {
          const int kcs = (kk >> 3) + quad;
          bf16x8 a[2], b[2];
          #pragma unroll
          for (int rt = 0; rt < 2; ++rt) {
            const int row = rt * 16 + m16;
            const int ch = ((k0i * 64 + kk) >> 3) + quad;
            a[rt] = *(const bf16x8*)&Ts[row * 512 + ((ch ^ (row & 7)) << 3)];
          }
          #pragma unroll
          for (int ct = 0; ct < 2; ++ct) {
            const int rl = ct * 16 + m16;
            b[ct] = *(const bf16x8*)&buf[rl * 64 + ((kcs ^ (rl & 7)) << 3)];
          }
          #pragma unroll
          for (int rt = 0; rt < 2; ++rt)
            #pragma unroll
            for (int ct = 0; ct < 2; ++ct)
              macc[rt][ct] = __builtin_amdgcn_mfma_f32_16x16x32_bf16(a[rt], b[ct], macc[rt][ct], 0, 0, 0);
        }
        WBAR();
        pb ^= 1;
      }
    }
    __syncthreads();  // Ts consumed by all waves; next expert may overwrite
  }

  // ---- epilogue ----
  #pragma unroll
  for (int rt = 0; rt < 2; ++rt)
    #pragma unroll
    for (int ct = 0; ct < 2; ++ct)
      #pragma unroll
      for (int i = 0; i < 4; ++i)
        MoeS[(rt * 16 + quad * 4 + i) * 256 + wcol + ct * 16 + m16] = macc[rt][ct][i];
  __syncthreads();

  float mv[16];
  float ss = 0.f;
  #pragma unroll
  for (int j = 0; j < 16; ++j) {
    mv[j] = MoeS[prow * 256 + pcol + j];
    ss += mv[j] * mv[j];
  }
  #pragma unroll
  for (int o = 8; o > 0; o >>= 1) ss += __shfl_xor(ss, o);
  const float r1 = rsqrtf(ss * (1.f / 256.f) + kEPS);
  float ss2 = 0.f;
  #pragma unroll
  for (int j = 0; j < 16; ++j) {
    hv[j] += wf[pcol + j] * mv[j] * r1;
    ss2 += hv[j] * hv[j];
  }
  #pragma unroll
  for (int o = 8; o > 0; o >>= 1) ss2 += __shfl_xor(ss2, o);
  const float r2 = rsqrtf(ss2 * (1.f / 256.f) + kEPS);

  const size_t base = (size_t)(r0 + prow) * 256 + pcol;
  #pragma unroll
  for (int j = 0; j < 16; j += 4)
    *(float4*)(h + base + j) = float4{hv[j], hv[j + 1], hv[j + 2], hv[j + 3]};
  #pragma unroll
  for (int j = 0; j < 16; j += 4) {
    *(ushort4*)(hb2 + base + j) = make_ushort4(f2b(hv[j]), f2b(hv[j + 1]), f2b(hv[j + 2]), f2b(hv[j + 3]));
    *(ushort4*)(hn + base + j) = make_ushort4(
        f2b(wa[pcol + j] * hv[j] * r2), f2b(wa[pcol + j + 1] * hv[j + 1] * r2),
        f2b(wa[pcol + j + 2] * hv[j + 2] * r2), f2b(wa[pcol + j + 3] * hv[j + 3] * r2));
  }
}

// ---------------- block-wide sum over 256 threads ----------------
__device__ __forceinline__ float block_sum256(float v) {
  #pragma unroll
  for (int o = 32; o > 0; o >>= 1) v += __shfl_down(v, o);
  __shared__ float red[4];
  __syncthreads();
  if ((threadIdx.x & 63) == 0) red[threadIdx.x >> 6] = v;
  __syncthreads();
  return red[0] + red[1] + red[2] + red[3];
}

__global__ __launch_bounds__(256) void rms_a_k(const float* __restrict__ h, const float* __restrict__ w,
                                               u16* __restrict__ hn) {
  const int l = blockIdx.x, t = threadIdx.x;
  const float v = h[(size_t)l * kDIM + t];
  const float ssum = block_sum256(v * v);
  const float r = rsqrtf(ssum * (1.f / 256.f) + kEPS);
  hn[(size_t)l * kDIM + t] = f2b(w[t] * v * r);
}

// causal depthwise conv (4 taps, 4 channels/thread) + bias + silu -> xcb; z*silu(z) -> zsb;
// also zeroes xdbl for the split-K atomic GEMM that follows.
__global__ __launch_bounds__(256) void conv_silu_k(const u16* __restrict__ xz, const float* __restrict__ cw,
                                                   const float* __restrict__ cb,
                                                   u16* __restrict__ xcb, u16* __restrict__ zsb,
                                                   float* __restrict__ xdbl) {
  const int i4 = blockIdx.x * 256 + threadIdx.x;  // L*DI/4
  if (i4 < 98304) *(float4*)&xdbl[i4 * 4] = float4{0.f, 0.f, 0.f, 0.f};
  const int l = i4 >> 7;
  const int d = (i4 & 127) * 4;
  float acc[4];
  const float4 cbv = *(const float4*)&cb[d];
  acc[0] = cbv.x; acc[1] = cbv.y; acc[2] = cbv.z; acc[3] = cbv.w;
  #pragma unroll
  for (int j = 0; j < 4; ++j) {
    const int ll = l - 3 + j;
    if (ll >= 0) {
      const ushort4 xv = *(const ushort4*)&xz[(size_t)ll * 1024 + d];
      acc[0] += cw[(d + 0) * 4 + j] * b2f(xv.x);
      acc[1] += cw[(d + 1) * 4 + j] * b2f(xv.y);
      acc[2] += cw[(d + 2) * 4 + j] * b2f(xv.z);
      acc[3] += cw[(d + 3) * 4 + j] * b2f(xv.w);
    }
  }
  ushort4 xo, zo;
  const ushort4 zv = *(const ushort4*)&xz[(size_t)l * 1024 + 512 + d];
  float z0 = b2f(zv.x), z1 = b2f(zv.y), z2 = b2f(zv.z), z3 = b2f(zv.w);
  xo.x = f2b(acc[0] * sigm(acc[0])); xo.y = f2b(acc[1] * sigm(acc[1]));
  xo.z = f2b(acc[2] * sigm(acc[2])); xo.w = f2b(acc[3] * sigm(acc[3]));
  zo.x = f2b(z0 * sigm(z0)); zo.y = f2b(z1 * sigm(z1));
  zo.z = f2b(z2 * sigm(z2)); zo.w = f2b(z3 * sigm(z3));
  *(ushort4*)&xcb[(size_t)l * 512 + d] = xo;
  *(ushort4*)&zsb[(size_t)l * 512 + d] = zo;
}

// ---------------- chunked selective scan; lane-pair state split ----------------
__global__ __launch_bounds__(256) void scan_a_k(const float* __restrict__ xdbl, const u16* __restrict__ xcb,
                                                const float* __restrict__ A_log, const float* __restrict__ dtw,
                                                const float* __restrict__ dtb,
                                                u16* __restrict__ delta,
                                                float* __restrict__ aprod, float* __restrict__ bacc) {
  const int c = blockIdx.x;
  const int t = threadIdx.x;
  const int half = t & 1;
  const int d = blockIdx.y * 128 + (t >> 1);
  const int l0 = c * 64;
  __shared__ float Xs[64][32];  // [lr][0:16)=dr, [16:32)=B
  for (int i = t; i < 2048; i += 256)
    Xs[i >> 5][i & 31] = xdbl[(size_t)(l0 + (i >> 5)) * 48 + (i & 31)];
  __syncthreads();
  float wd[8], Ad[8];
  #pragma unroll
  for (int j = 0; j < 8; ++j) wd[j] = dtw[d * 16 + half * 8 + j];
  const float bd = dtb[d];
  #pragma unroll
  for (int n = 0; n < 8; ++n) Ad[n] = -__expf(A_log[d * 16 + half * 8 + n]);
  float s[8], ap[8];
  #pragma unroll
  for (int n = 0; n < 8; ++n) { s[n] = 0.f; ap[n] = 1.f; }
  #pragma unroll 4
  for (int lr = 0; lr < 64; ++lr) {
    const float4 dr0 = *(const float4*)&Xs[lr][half * 8];
    const float4 dr1 = *(const float4*)&Xs[lr][half * 8 + 4];
    float p0 = dr0.x * wd[0] + dr0.y * wd[1] + dr0.z * wd[2] + dr0.w * wd[3];
    float p1 = dr1.x * wd[4] + dr1.y * wd[5] + dr1.z * wd[6] + dr1.w * wd[7];
    float dot = p0 + p1;
    dot += __shfl_xor(dot, 1);
    const float dl = softplus_fast(dot + bd);
    const int l = l0 + lr;
    if (!half) delta[(size_t)l * 512 + d] = f2b(dl);
    const float du = dl * b2f(xcb[(size_t)l * 512 + d]);
    const float4 B0 = *(const float4*)&Xs[lr][16 + half * 8];
    const float4 B1 = *(const float4*)&Xs[lr][16 + half * 8 + 4];
    const float Bv[8] = {B0.x, B0.y, B0.z, B0.w, B1.x, B1.y, B1.z, B1.w};
    #pragma unroll
    for (int n = 0; n < 8; ++n) {
      const float a = __expf(dl * Ad[n]);
      s[n] = fmaf(a, s[n], du * Bv[n]);
      ap[n] *= a;
    }
  }
  const int base = c * 8192 + d * 16 + half * 8;
  #pragma unroll
  for (int n = 0; n < 8; ++n) { aprod[base + n] = ap[n]; bacc[base + n] = s[n]; }
}

// chunk combine levels 1+2: 128 chunks = 16 groups x 8
__global__ __launch_bounds__(256) void scan_b1_k(const float* __restrict__ aprod, const float* __restrict__ bacc,
                                                 float* __restrict__ gp, float* __restrict__ gb) {
  const int idx = blockIdx.x * 256 + threadIdx.x;  // 8192*16
  const int st = idx & 8191, g = idx >> 13;
  float P = 1.f, S = 0.f;
  #pragma unroll
  for (int k = 0; k < 8; ++k) {
    const int c = g * 8 + k;
    const float a = aprod[(size_t)c * 8192 + st];
    S = fmaf(a, S, bacc[(size_t)c * 8192 + st]);
    P *= a;
  }
  gp[(size_t)g * 8192 + st] = P;
  gb[(size_t)g * 8192 + st] = S;
}

__global__ __launch_bounds__(256) void scan_b2_k(const float* __restrict__ gp, const float* __restrict__ gb,
                                                 float* __restrict__ ginit) {
  const int st = blockIdx.x * 256 + threadIdx.x;  // 8192
  float cur = 0.f;
  #pragma unroll
  for (int g = 0; g < 16; ++g) {
    ginit[(size_t)g * 8192 + st] = cur;
    cur = fmaf(gp[(size_t)g * 8192 + st], cur, gb[(size_t)g * 8192 + st]);
  }
}

// scan_c with inlined level-3 combine (reads ginit + folds <=7 chunk partials)
__global__ __launch_bounds__(256) void scan_c_k(const float* __restrict__ xdbl, const u16* __restrict__ xcb,
                                                const u16* __restrict__ zsb, const float* __restrict__ A_log,
                                                const u16* __restrict__ delta,
                                                const float* __restrict__ aprod, const float* __restrict__ bacc,
                                                const float* __restrict__ ginit,
                                                const float* __restrict__ Dp, u16* __restrict__ yv) {
  const int c = blockIdx.x;
  const int t = threadIdx.x;
  const int half = t & 1;
  const int d = blockIdx.y * 128 + (t >> 1);
  const int l0 = c * 64;
  __shared__ float Xs[64][32];  // [lr][0:16)=B, [16:32)=C
  for (int i = t; i < 2048; i += 256)
    Xs[i >> 5][i & 31] = xdbl[(size_t)(l0 + (i >> 5)) * 48 + 16 + (i & 31)];
  __syncthreads();
  float Ad[8];
  #pragma unroll
  for (int n = 0; n < 8; ++n) Ad[n] = -__expf(A_log[d * 16 + half * 8 + n]);
  float s[8];
  {
    const int g = c >> 3;
    const int stb = d * 16 + half * 8;
    const float4 g0 = *(const float4*)&ginit[(size_t)g * 8192 + stb];
    const float4 g1 = *(const float4*)&ginit[(size_t)g * 8192 + stb + 4];
    s[0] = g0.x; s[1] = g0.y; s[2] = g0.z; s[3] = g0.w;
    s[4] = g1.x; s[5] = g1.y; s[6] = g1.z; s[7] = g1.w;
    for (int cc = g * 8; cc < c; ++cc) {
      const float4 a0 = *(const float4*)&aprod[(size_t)cc * 8192 + stb];
      const float4 a1 = *(const float4*)&aprod[(size_t)cc * 8192 + stb + 4];
      const float4 b0 = *(const float4*)&bacc[(size_t)cc * 8192 + stb];
      const float4 b1 = *(const float4*)&bacc[(size_t)cc * 8192 + stb + 4];
      s[0] = fmaf(a0.x, s[0], b0.x); s[1] = fmaf(a0.y, s[1], b0.y);
      s[2] = fmaf(a0.z, s[2], b0.z); s[3] = fmaf(a0.w, s[3], b0.w);
      s[4] = fmaf(a1.x, s[4], b1.x); s[5] = fmaf(a1.y, s[5], b1.y);
      s[6] = fmaf(a1.z, s[6], b1.z); s[7] = fmaf(a1.w, s[7], b1.w);
    }
  }
  const float Dd = Dp[d];
  #pragma unroll 4
  for (int lr = 0; lr < 64; ++lr) {
    const int l = l0 + lr;
    const float dl = b2f(delta[(size_t)l * 512 + d]);
    const float xv = b2f(xcb[(size_t)l * 512 + d]);
    const float zs = b2f(zsb[(size_t)l * 512 + d]);
    const float du = dl * xv;
    const float4 B0 = *(const float4*)&Xs[lr][half * 8];
    const float4 B1 = *(const float4*)&Xs[lr][half * 8 + 4];
    const float4 C0 = *(const float4*)&Xs[lr][16 + half * 8];
    const float4 C1 = *(const float4*)&Xs[lr][16 + half * 8 + 4];
    const float Bv[8] = {B0.x, B0.y, B0.z, B0.w, B1.x, B1.y, B1.z, B1.w};
    const float Cv[8] = {C0.x, C0.y, C0.z, C0.w, C1.x, C1.y, C1.z, C1.w};
    float y = 0.f;
    #pragma unroll
    for (int n = 0; n < 8; ++n) {
      const float a = __expf(dl * Ad[n]);
      s[n] = fmaf(a, s[n], du * Bv[n]);
      y = fmaf(s[n], Cv[n], y);
    }
    y += __shfl_xor(y, 1);
    if (!half) yv[(size_t)l * 512 + d] = f2b((y + xv * Dd) * zs);
  }
}

extern "C" void kernel_launch(void* const* d_in, const int* in_sizes, int n_in,
                              void* d_out, int out_size, void* d_ws, size_t ws_size,
                              hipStream_t stream) {
  const float* x        = (const float*)d_in[0];
  const float* lin_w    = (const float*)d_in[1];
  const float* in_proj  = (const float*)d_in[2];
  const float* conv_w   = (const float*)d_in[3];
  const float* conv_b   = (const float*)d_in[4];
  const float* x_proj   = (const float*)d_in[5];
  const float* dt_w     = (const float*)d_in[6];
  const float* dt_b     = (const float*)d_in[7];
  const float* A_log    = (const float*)d_in[8];
  const float* D_param  = (const float*)d_in[9];
  const float* out_proj = (const float*)d_in[10];
  const float* gate_w   = (const float*)d_in[11];
  const float* gproj    = (const float*)d_in[12];
  const float* uproj    = (const float*)d_in[13];
  const float* dproj    = (const float*)d_in[14];
  const float* rms_a_w  = (const float*)d_in[15];
  const float* rms_f_w  = (const float*)d_in[16];
  const float* head_w1  = (const float*)d_in[17];
  const float* head_w2  = (const float*)d_in[18];

  char* p = (char*)d_ws;
  auto alloc = [&](size_t bytes) -> char* {
    char* r = p;
    p += (bytes + 255) & ~(size_t)255;
    return r;
  };

  // bf16 weight pool
  u16* lin_b  = (u16*)alloc(65536 * 2);
  u16* ipw_b  = (u16*)alloc((size_t)2097152 * 2);
  u16* xpw_b  = (u16*)alloc((size_t)196608 * 2);
  u16* opw_b  = (u16*)alloc((size_t)1048576 * 2);
  u16* gupw_b = (u16*)alloc((size_t)8388608 * 2);  // 16-wide gu interleave, expert-grouped
  u16* dpw_b  = (u16*)alloc((size_t)4194304 * 2);
  u16* hw1_b  = (u16*)alloc(65536 * 2);
  u16* hw2_b  = (u16*)alloc(8192 * 2);

  // activations
  u16* xT     = (u16*)alloc((size_t)kL * kDIM * 2);
  float* h    = (float*)alloc((size_t)kL * kDIM * 4);
  u16* hn     = (u16*)alloc((size_t)kL * kDIM * 2);
  u16* hb2    = (u16*)alloc((size_t)kL * kDIM * 2);
  float* xdbl = (float*)alloc((size_t)kL * 48 * 4);
  u16* fb     = (u16*)alloc((size_t)kL * kDIM * 2);
  u16* h2b    = (u16*)alloc((size_t)kL * kDIM * 2);
  u16* xz     = (u16*)alloc((size_t)kL * 1024 * 2);
  u16* xcb    = (u16*)alloc((size_t)kL * kDI * 2);
  u16* zsb    = (u16*)alloc((size_t)kL * kDI * 2);
  u16* yv     = (u16*)alloc((size_t)kL * kDI * 2);
  u16* delta  = (u16*)alloc((size_t)kL * kDI * 2);
  float* aprod = (float*)alloc((size_t)128 * 8192 * 4);
  float* bacc  = (float*)alloc((size_t)128 * 8192 * 4);
  float* gp    = (float*)alloc((size_t)16 * 8192 * 4);
  float* gb    = (float*)alloc((size_t)16 * 8192 * 4);
  float* ginit = (float*)alloc((size_t)16 * 8192 * 4);

  if ((size_t)(p - (char*)d_ws) > ws_size) return;  // fail loudly

  // ---- weight conversion ----
  Cvt2 dd;
  int seg = 0, blk = 0;
  auto add = [&](const float* s, u16* d, int n, int mode) {
    dd.s[seg] = s; dd.d[seg] = d; dd.n[seg] = n; dd.mode[seg] = mode;
    dd.bstart[seg] = blk;
    blk += (n + 4095) / 4096;
    ++seg;
  };
  add(lin_w, lin_b, 65536, 0);
  add(in_proj, ipw_b, 2097152, 0);
  add(x_proj, xpw_b, 196608, 0);
  add(out_proj, opw_b, 1048576, 0);
  add(head_w1, hw1_b, 65536, 0);
  add(head_w2, hw2_b, 8192, 0);
  for (int i = 0; i < kNB; ++i) {
    add(gproj + (size_t)i * 524288, gupw_b + (size_t)i * 1048576, 524288, 1);
    add(uproj + (size_t)i * 524288, gupw_b + (size_t)i * 1048576 + 4096, 524288, 1);
  }
  add(dproj, dpw_b, 4194304, 2);
  dd.nseg = seg;
  dd.bstart[seg] = blk;
  cvt2_k<<<blk, 256, 0, stream>>>(dd);
  transpose_x_k<<<dim3(kL / 32, kDIM / 32), dim3(32, 8), 0, stream>>>(x, xT);

  // h = xT @ lin_w^T
  gemm_t<64, 128, 2, 4, 2, 0><<<dim3(128, 2, 1), 256, 0, stream>>>(
      xT, 256, lin_b, 256, h, 256, 256, 256, 0);
  rms_a_k<<<kL, 256, 0, stream>>>(h, rms_a_w, hn);

  for (int i = 0; i < kNB; ++i) {
    // in_proj: N=1024, K=256 -> xz bf16
    gemm_t<128, 128, 4, 4, 2, 2><<<dim3(64, 8, 1), 256, 0, stream>>>(
        hn, 256, ipw_b + (size_t)i * 262144, 256, xz, 1024, 1024, 256, 0);
    conv_silu_k<<<kL * kDI / 1024, 256, 0, stream>>>(xz, conv_w + (size_t)i * 2048,
                                                     conv_b + (size_t)i * 512, xcb, zsb, xdbl);
    // xdbl: N=48, K=512, split-K=8 atomic (xdbl zeroed by conv kernel)
    gemm_t<128, 48, 2, 3, 1, 4><<<dim3(64, 1, 8), 256, 0, stream>>>(
        xcb, 512, xpw_b + (size_t)i * 24576, 512, xdbl, 48, 48, 512, 0);
    scan_a_k<<<dim3(128, 4), 256, 0, stream>>>(xdbl, xcb, A_log + (size_t)i * 8192,
                                               dt_w + (size_t)i * 8192, dt_b + (size_t)i * 512,
                                               delta, aprod, bacc);
    scan_b1_k<<<512, 256, 0, stream>>>(aprod, bacc, gp, gb);
    scan_b2_k<<<32, 256, 0, stream>>>(gp, gb, ginit);
    scan_c_k<<<dim3(128, 4), 256, 0, stream>>>(xdbl, xcb, zsb, A_log + (size_t)i * 8192,
                                               delta, aprod, bacc, ginit,
                                               D_param + (size_t)i * 512, yv);
    // fused mega: out_proj + router + gu + GLU + dproj + rms_f + rms_a
    moe_mega_k<<<256, 512, 0, stream>>>(h, yv, opw_b + (size_t)i * 131072,
                                        gate_w + (size_t)i * 1024,
                                        gupw_b + (size_t)i * 1048576, dpw_b + (size_t)i * 524288,
                                        rms_f_w, rms_a_w, hb2, hn);
  }

  // head: lin -> silu(head1) -> head2 + sigmoid-transpose fused
  gemm_t<64, 128, 2, 4, 2, 2><<<dim3(128, 2, 1), 256, 0, stream>>>(
      hb2, 256, lin_b, 256, h2b, 256, 256, 256, 0);
  gemm_t<64, 128, 2, 4, 2, 3><<<dim3(128, 2, 1), 256, 0, stream>>>(
      h2b, 256, hw1_b, 256, fb, 256, 256, 256, 0);
  gemm_t<64, 128, 2, 4, 2, 7><<<dim3(128, 1, 1), 256, 0, stream>>>(
      fb, 256, hw2_b, 256, (float*)d_out, 32, 32, 256, 0);
}